// Round 2
// baseline (953.638 us; speedup 1.0000x reference)
//
#include <hip/hip_runtime.h>
#include <hip/hip_bf16.h>

#define NPOI 50000
#define EMB 128
#define NEDGE 800000
#define EAUG (2 * NEDGE + NPOI)
#define BATCH 512
#define SEQL 64
#define NHEADS 4
#define HDIM 32

// ---------------- degree / CSR build ----------------

__global__ void init_counts_kernel(int* __restrict__ counts) {
    int i = blockIdx.x * blockDim.x + threadIdx.x;
    if (i < NPOI) counts[i] = 1;  // self loop
}

__global__ void count_edges_kernel(const int* __restrict__ e0, const int* __restrict__ e1,
                                   int* __restrict__ counts) {
    int e = blockIdx.x * blockDim.x + threadIdx.x;
    if (e < NEDGE) {
        atomicAdd(&counts[e0[e]], 1);
        atomicAdd(&counts[e1[e]], 1);
    }
}

__global__ void rsqrt_deg_kernel(const int* __restrict__ counts, float* __restrict__ rd) {
    int i = blockIdx.x * blockDim.x + threadIdx.x;
    if (i < NPOI) rd[i] = rsqrtf((float)counts[i]);
}

// single-block exclusive scan of counts -> offs[0..NPOI], cursor copy
__global__ __launch_bounds__(1024) void scan_kernel(const int* __restrict__ counts,
                                                    int* __restrict__ offs,
                                                    int* __restrict__ cursor) {
    const int CHUNK = (NPOI + 1023) / 1024;  // 49
    __shared__ int part[1024];
    int t = threadIdx.x;
    int start = t * CHUNK;
    int end = start + CHUNK; if (end > NPOI) end = NPOI;
    int s = 0;
    for (int i = start; i < end && i < NPOI; ++i) s += counts[i];
    part[t] = s;
    __syncthreads();
    for (int o = 1; o < 1024; o <<= 1) {
        int v = (t >= o) ? part[t - o] : 0;
        __syncthreads();
        part[t] += v;
        __syncthreads();
    }
    int base = (t == 0) ? 0 : part[t - 1];
    for (int i = start; i < end && i < NPOI; ++i) {
        offs[i] = base;
        cursor[i] = base;
        base += counts[i];
    }
    if (t == 0) offs[NPOI] = part[1023];
}

__global__ void fill_kernel(const int* __restrict__ e0, const int* __restrict__ e1,
                            const float* __restrict__ dv, const float* __restrict__ rd,
                            int* __restrict__ cursor, int* __restrict__ col,
                            float* __restrict__ wv) {
    int e = blockIdx.x * blockDim.x + threadIdx.x;
    if (e >= EAUG) return;
    int s, d; float dist;
    if (e < NEDGE)          { s = e0[e];          d = e1[e];          dist = dv[e]; }
    else if (e < 2 * NEDGE) { int i = e - NEDGE;  s = e1[i]; d = e0[i]; dist = dv[i]; }
    else                    { s = e - 2 * NEDGE;  d = s;              dist = 0.f; }
    float w = rd[s] * rd[d] * expf(-dist * dist);
    int pos = atomicAdd(&cursor[s], 1);
    col[pos] = d;
    wv[pos] = w;
}

// ---------------- fp32 GEMM: C[M,N] = A(gathered)[M,128] @ B[N,128]^T + bias ----------------

__global__ __launch_bounds__(256) void gemm_bt_k128(
    const float* __restrict__ A, const int* __restrict__ gidx,
    const float* __restrict__ B, const float* __restrict__ bias,
    float* __restrict__ C, int M, int N)
{
    __shared__ float As[128][64];  // k-major, stride 64: staging writes hit bank r%32 (2-way, free)
    __shared__ float Bs[128][64];
    const int tid = threadIdx.x;
    const int m0 = blockIdx.x * 64;
    const int n0 = blockIdx.y * 64;

#pragma unroll
    for (int i = 0; i < 8; ++i) {
        int f = i * 256 + tid;
        int r = f & 63;
        int kq = f >> 6;  // 0..31
        float4 av = make_float4(0.f, 0.f, 0.f, 0.f);
        int gm = m0 + r;
        if (gm < M) {
            int ar = gidx ? gidx[gm] : gm;
            av = *(const float4*)(A + (size_t)ar * 128 + kq * 4);
        }
        As[kq * 4 + 0][r] = av.x; As[kq * 4 + 1][r] = av.y;
        As[kq * 4 + 2][r] = av.z; As[kq * 4 + 3][r] = av.w;
        float4 bv = *(const float4*)(B + (size_t)(n0 + r) * 128 + kq * 4);
        Bs[kq * 4 + 0][r] = bv.x; Bs[kq * 4 + 1][r] = bv.y;
        Bs[kq * 4 + 2][r] = bv.z; Bs[kq * 4 + 3][r] = bv.w;
    }
    __syncthreads();

    const int tx = tid & 15;   // col group
    const int ty = tid >> 4;   // row group
    float acc[4][4];
#pragma unroll
    for (int i = 0; i < 4; ++i)
#pragma unroll
        for (int j = 0; j < 4; ++j) acc[i][j] = 0.f;

#pragma unroll 8
    for (int k = 0; k < 128; ++k) {
        float a4[4], b4[4];
        *(float4*)a4 = *(const float4*)&As[k][ty * 4];  // broadcast across tx
        *(float4*)b4 = *(const float4*)&Bs[k][tx * 4];  // 2-way (free)
#pragma unroll
        for (int i = 0; i < 4; ++i)
#pragma unroll
            for (int j = 0; j < 4; ++j) acc[i][j] += a4[i] * b4[j];
    }

#pragma unroll
    for (int i = 0; i < 4; ++i) {
        int gm = m0 + ty * 4 + i;
        if (gm >= M) continue;
        int gn = n0 + tx * 4;
        float4 o;
        o.x = acc[i][0] + bias[gn + 0];
        o.y = acc[i][1] + bias[gn + 1];
        o.z = acc[i][2] + bias[gn + 2];
        o.w = acc[i][3] + bias[gn + 3];
        *(float4*)(C + (size_t)gm * N + gn) = o;
    }
}

// ---------------- CSR aggregate + leaky-relu + L2 normalize ----------------

__global__ __launch_bounds__(128) void aggregate_kernel(
    const float* __restrict__ h, const int* __restrict__ offs,
    const int* __restrict__ col, const float* __restrict__ wv,
    float* __restrict__ enc_out)
{
    const int row = blockIdx.x;
    const int c = threadIdx.x;  // 0..127
    const int beg = offs[row];
    const int end = offs[row + 1];
    float acc = 0.f;
    for (int e = beg; e < end; ++e) {
        int d = col[e];        // uniform across block -> scalar load
        float w = wv[e];
        acc += w * h[(size_t)d * 128 + c];
    }
    acc = acc >= 0.f ? acc : 0.01f * acc;  // leaky_relu
    __shared__ float red[128];
    red[c] = acc * acc;
    __syncthreads();
    for (int o = 64; o > 0; o >>= 1) {
        if (c < o) red[c] += red[c + o];
        __syncthreads();
    }
    float norm = fmaxf(sqrtf(red[0]), 1e-12f);
    enc_out[(size_t)row * 128 + c] = acc / norm;
}

// ---------------- attention per (session, head); accumulates mean over L ----------------

__global__ __launch_bounds__(64) void attn_kernel(const float* __restrict__ qkv,
                                                  float* __restrict__ obar)
{
    const int b = blockIdx.x;
    const int h = blockIdx.y;
    const int l = threadIdx.x;  // 0..63
    __shared__ float ks[64][33];
    __shared__ float vs[64][33];
    __shared__ float os[64][33];
    const float* base = qkv + (size_t)b * SEQL * 384;
    float q[32];
#pragma unroll
    for (int j0 = 0; j0 < 32; j0 += 4) {
        float4 qv = *(const float4*)(base + (size_t)l * 384 + h * 32 + j0);
        q[j0 + 0] = qv.x; q[j0 + 1] = qv.y; q[j0 + 2] = qv.z; q[j0 + 3] = qv.w;
        float4 kv = *(const float4*)(base + (size_t)l * 384 + 128 + h * 32 + j0);
        ks[l][j0 + 0] = kv.x; ks[l][j0 + 1] = kv.y; ks[l][j0 + 2] = kv.z; ks[l][j0 + 3] = kv.w;
        float4 vv = *(const float4*)(base + (size_t)l * 384 + 256 + h * 32 + j0);
        vs[l][j0 + 0] = vv.x; vs[l][j0 + 1] = vv.y; vs[l][j0 + 2] = vv.z; vs[l][j0 + 3] = vv.w;
    }
    __syncthreads();

    const float scale = 0.17677669529663687f;  // 1/sqrt(32)
    float s[64];
    float mx = -1e30f;
#pragma unroll
    for (int m = 0; m < 64; ++m) {
        float acc = 0.f;
#pragma unroll
        for (int j = 0; j < 32; ++j) acc += q[j] * ks[m][j];
        acc *= scale;
        s[m] = acc;
        mx = fmaxf(mx, acc);
    }
    float sum = 0.f;
#pragma unroll
    for (int m = 0; m < 64; ++m) { float e = __expf(s[m] - mx); s[m] = e; sum += e; }
    float inv = 1.f / sum;
    float o[32];
#pragma unroll
    for (int j = 0; j < 32; ++j) o[j] = 0.f;
#pragma unroll
    for (int m = 0; m < 64; ++m) {
        float p = s[m] * inv;
#pragma unroll
        for (int j = 0; j < 32; ++j) o[j] += p * vs[m][j];
    }
#pragma unroll
    for (int j = 0; j < 32; ++j) os[l][j] = o[j];
    __syncthreads();
    if (l < 32) {
        float acc = 0.f;
#pragma unroll
        for (int m = 0; m < 64; ++m) acc += os[m][l];
        obar[(size_t)b * 128 + h * 32 + l] = acc * (1.f / 64.f);
    }
}

// ---------------- epilogue: fp32 outputs (reference output dtype is float32) ----------------

__global__ void finalize_kernel(const float* __restrict__ aggr, const float* __restrict__ enc,
                                const int* __restrict__ data_poi, float* __restrict__ out)
{
    int i = blockIdx.x * blockDim.x + threadIdx.x;  // 0..131071
    if (i < BATCH * 128) {
        out[i] = aggr[i];
    } else {
        int j = i - BATCH * 128;
        int r = j >> 7, c = j & 127;
        out[i] = enc[(size_t)data_poi[r] * 128 + c];
    }
}

// ---------------- launch ----------------

extern "C" void kernel_launch(void* const* d_in, const int* in_sizes, int n_in,
                              void* d_out, int out_size, void* d_ws, size_t ws_size,
                              hipStream_t stream)
{
    const float* poi      = (const float*)d_in[0];
    const int*   edges    = (const int*)d_in[1];   // [2][NEDGE]
    const float* dvec     = (const float*)d_in[2];
    const int*   data_poi = (const int*)d_in[3];
    const int*   data_x   = (const int*)d_in[4];
    const float* lin_w    = (const float*)d_in[5];
    const float* lin_b    = (const float*)d_in[6];
    const float* inw      = (const float*)d_in[7];
    const float* inb      = (const float*)d_in[8];
    const float* outw     = (const float*)d_in[9];
    const float* outb     = (const float*)d_in[10];
    const int* e0 = edges;
    const int* e1 = edges + NEDGE;

    char* ws = (char*)d_ws;
    size_t off = 0;
    auto alloc = [&](size_t bytes) -> void* {
        void* p = ws + off;
        off = (off + bytes + 255) & ~(size_t)255;
        return p;
    };
    int*   counts = (int*)  alloc(NPOI * 4);
    int*   offs   = (int*)  alloc((NPOI + 1) * 4);
    int*   cursor = (int*)  alloc(NPOI * 4);
    float* rd     = (float*)alloc(NPOI * 4);
    int*   col    = (int*)  alloc((size_t)EAUG * 4);
    float* wv     = (float*)alloc((size_t)EAUG * 4);
    float* hbuf   = (float*)alloc((size_t)NPOI * 128 * 4);
    float* enc    = (float*)alloc((size_t)NPOI * 128 * 4);
    float* qkvb   = (float*)alloc((size_t)BATCH * SEQL * 384 * 4);
    float* obar   = (float*)alloc((size_t)BATCH * 128 * 4);
    float* aggr   = (float*)alloc((size_t)BATCH * 128 * 4);

    // graph structure
    init_counts_kernel<<<(NPOI + 255) / 256, 256, 0, stream>>>(counts);
    count_edges_kernel<<<(NEDGE + 255) / 256, 256, 0, stream>>>(e0, e1, counts);
    rsqrt_deg_kernel<<<(NPOI + 255) / 256, 256, 0, stream>>>(counts, rd);
    scan_kernel<<<1, 1024, 0, stream>>>(counts, offs, cursor);
    fill_kernel<<<(EAUG + 255) / 256, 256, 0, stream>>>(e0, e1, dvec, rd, cursor, col, wv);

    // 2 graph-conv layers
    for (int l = 0; l < 2; ++l) {
        const float* a = (l == 0) ? poi : enc;
        gemm_bt_k128<<<dim3((NPOI + 63) / 64, 2), 256, 0, stream>>>(
            a, nullptr, lin_w + (size_t)l * 128 * 128, lin_b + (size_t)l * 128,
            hbuf, NPOI, 128);
        aggregate_kernel<<<NPOI, 128, 0, stream>>>(hbuf, offs, col, wv, enc);
    }

    // attention
    gemm_bt_k128<<<dim3(BATCH * SEQL / 64, 6), 256, 0, stream>>>(
        enc, data_x, inw, inb, qkvb, BATCH * SEQL, 384);
    attn_kernel<<<dim3(BATCH, NHEADS), 64, 0, stream>>>(qkvb, obar);
    gemm_bt_k128<<<dim3(BATCH / 64, 2), 256, 0, stream>>>(
        obar, nullptr, outw, outb, aggr, BATCH, 128);

    finalize_kernel<<<(2 * BATCH * 128 + 255) / 256, 256, 0, stream>>>(
        aggr, enc, data_poi, (float*)d_out);
}

// Round 3
// 565.973 us; speedup vs baseline: 1.6850x; 1.6850x over previous
//
#include <hip/hip_runtime.h>
#include <hip/hip_bf16.h>
#include <hip/hip_fp16.h>
#include <type_traits>

#define NPOI 50000
#define EMB 128
#define NEDGE 800000
#define EAUG (2 * NEDGE + NPOI)
#define BATCH 512
#define SEQL 64
#define NHEADS 4
#define HDIM 32
#define SCAN_BLOCKS ((NPOI + 255) / 256)   // 196

// ---------------- degree / CSR build ----------------

__global__ void init_counts_kernel(int* __restrict__ counts) {
    int i = blockIdx.x * blockDim.x + threadIdx.x;
    if (i < NPOI) counts[i] = 1;  // self loop
}

__global__ void count_edges_kernel(const int* __restrict__ e0, const int* __restrict__ e1,
                                   int* __restrict__ counts) {
    int e = blockIdx.x * blockDim.x + threadIdx.x;
    if (e < NEDGE) {
        atomicAdd(&counts[e0[e]], 1);
        atomicAdd(&counts[e1[e]], 1);
    }
}

__global__ void rsqrt_deg_kernel(const int* __restrict__ counts, float* __restrict__ rd) {
    int i = blockIdx.x * blockDim.x + threadIdx.x;
    if (i < NPOI) rd[i] = rsqrtf((float)counts[i]);
}

// coalesced hierarchical scan: block sums -> mid scan -> per-chunk scan
__global__ __launch_bounds__(256) void block_sum_kernel(const int* __restrict__ counts,
                                                        int* __restrict__ bsum) {
    __shared__ int sh[256];
    int i = blockIdx.x * 256 + threadIdx.x;
    sh[threadIdx.x] = (i < NPOI) ? counts[i] : 0;
    __syncthreads();
    for (int o = 128; o > 0; o >>= 1) {
        if (threadIdx.x < o) sh[threadIdx.x] += sh[threadIdx.x + o];
        __syncthreads();
    }
    if (threadIdx.x == 0) bsum[blockIdx.x] = sh[0];
}

__global__ __launch_bounds__(256) void scan_mid_kernel(const int* __restrict__ bsum,
                                                       int* __restrict__ bbase) {
    __shared__ int sh[256];
    int t = threadIdx.x;
    int v = (t < SCAN_BLOCKS) ? bsum[t] : 0;
    sh[t] = v;
    __syncthreads();
    for (int o = 1; o < 256; o <<= 1) {
        int u = (t >= o) ? sh[t - o] : 0;
        __syncthreads();
        sh[t] += u;
        __syncthreads();
    }
    if (t < SCAN_BLOCKS) bbase[t] = sh[t] - v;  // exclusive
}

__global__ __launch_bounds__(256) void scan_chunk_kernel(const int* __restrict__ counts,
                                                         const int* __restrict__ bbase,
                                                         int* __restrict__ offs,
                                                         int* __restrict__ cursor) {
    __shared__ int sh[256];
    int b = blockIdx.x, t = threadIdx.x;
    int i = b * 256 + t;
    int v = (i < NPOI) ? counts[i] : 0;
    sh[t] = v;
    __syncthreads();
    for (int o = 1; o < 256; o <<= 1) {
        int u = (t >= o) ? sh[t - o] : 0;
        __syncthreads();
        sh[t] += u;
        __syncthreads();
    }
    int excl = sh[t] - v + bbase[b];
    if (i < NPOI) {
        offs[i] = excl;
        cursor[i] = excl;
        if (i == NPOI - 1) offs[NPOI] = excl + v;
    }
}

// fill CSR with packed (dst, weight)
__global__ void fill_kernel(const int* __restrict__ e0, const int* __restrict__ e1,
                            const float* __restrict__ dv, const float* __restrict__ rd,
                            int* __restrict__ cursor, int2* __restrict__ ew) {
    int e = blockIdx.x * blockDim.x + threadIdx.x;
    if (e >= EAUG) return;
    int s, d; float dist;
    if (e < NEDGE)          { s = e0[e];          d = e1[e];          dist = dv[e]; }
    else if (e < 2 * NEDGE) { int i = e - NEDGE;  s = e1[i]; d = e0[i]; dist = dv[i]; }
    else                    { s = e - 2 * NEDGE;  d = s;              dist = 0.f; }
    float w = rd[s] * rd[d] * expf(-dist * dist);
    int pos = atomicAdd(&cursor[s], 1);
    ew[pos] = make_int2(d, __float_as_int(w));
}

// ---------------- fp32 GEMM: C[M,N] = A(gathered)[M,128] @ B[N,128]^T + bias ----------------

template <typename OutT>
__device__ inline void store4(OutT* C, size_t idx, float4 o) {
    if constexpr (std::is_same<OutT, __half>::value) {
        __half2 p0 = __floats2half2_rn(o.x, o.y);
        __half2 p1 = __floats2half2_rn(o.z, o.w);
        *(__half2*)(C + idx) = p0;
        *(__half2*)(C + idx + 2) = p1;
    } else {
        *(float4*)(C + idx) = o;
    }
}

template <typename OutT>
__global__ __launch_bounds__(256) void gemm_bt_k128(
    const float* __restrict__ A, const int* __restrict__ gidx,
    const float* __restrict__ B, const float* __restrict__ bias,
    OutT* __restrict__ C, int M, int N)
{
    __shared__ float As[128][64];  // k-major, stride 64: staging writes hit bank r%32 (2-way, free)
    __shared__ float Bs[128][64];
    const int tid = threadIdx.x;
    const int m0 = blockIdx.x * 64;
    const int n0 = blockIdx.y * 64;

#pragma unroll
    for (int i = 0; i < 8; ++i) {
        int f = i * 256 + tid;
        int r = f & 63;
        int kq = f >> 6;  // 0..31
        float4 av = make_float4(0.f, 0.f, 0.f, 0.f);
        int gm = m0 + r;
        if (gm < M) {
            int ar = gidx ? gidx[gm] : gm;
            av = *(const float4*)(A + (size_t)ar * 128 + kq * 4);
        }
        As[kq * 4 + 0][r] = av.x; As[kq * 4 + 1][r] = av.y;
        As[kq * 4 + 2][r] = av.z; As[kq * 4 + 3][r] = av.w;
        float4 bv = *(const float4*)(B + (size_t)(n0 + r) * 128 + kq * 4);
        Bs[kq * 4 + 0][r] = bv.x; Bs[kq * 4 + 1][r] = bv.y;
        Bs[kq * 4 + 2][r] = bv.z; Bs[kq * 4 + 3][r] = bv.w;
    }
    __syncthreads();

    const int tx = tid & 15;   // col group
    const int ty = tid >> 4;   // row group
    float acc[4][4];
#pragma unroll
    for (int i = 0; i < 4; ++i)
#pragma unroll
        for (int j = 0; j < 4; ++j) acc[i][j] = 0.f;

#pragma unroll 8
    for (int k = 0; k < 128; ++k) {
        float a4[4], b4[4];
        *(float4*)a4 = *(const float4*)&As[k][ty * 4];  // broadcast across tx
        *(float4*)b4 = *(const float4*)&Bs[k][tx * 4];  // 2-way (free)
#pragma unroll
        for (int i = 0; i < 4; ++i)
#pragma unroll
            for (int j = 0; j < 4; ++j) acc[i][j] += a4[i] * b4[j];
    }

#pragma unroll
    for (int i = 0; i < 4; ++i) {
        int gm = m0 + ty * 4 + i;
        if (gm >= M) continue;
        int gn = n0 + tx * 4;
        float4 o;
        o.x = acc[i][0] + bias[gn + 0];
        o.y = acc[i][1] + bias[gn + 1];
        o.z = acc[i][2] + bias[gn + 2];
        o.w = acc[i][3] + bias[gn + 3];
        store4(C, (size_t)gm * N + gn, o);
    }
}

// ---------------- CSR aggregate + leaky-relu + L2 normalize ----------------
// one wave per row; h in fp16 (halves gather traffic; |h|<~8 so fp16 is safe, err ~5e-4 rel)

__global__ __launch_bounds__(64) void aggregate_kernel(
    const __half* __restrict__ h, const int* __restrict__ offs,
    const int2* __restrict__ ew, float* __restrict__ enc_out)
{
    const int row = blockIdx.x;
    const int lane = threadIdx.x;  // 0..63, handles cols 2*lane, 2*lane+1
    const int beg = offs[row];
    const int end = offs[row + 1];
    float ax = 0.f, ay = 0.f;
#pragma unroll 2
    for (int e = beg; e < end; ++e) {
        int2 p = ew[e];                         // broadcast (uniform addr)
        float w = __int_as_float(p.y);
        __half2 hv = *(const __half2*)(h + (size_t)p.x * 128 + lane * 2);
        float2 f = __half22float2(hv);
        ax += w * f.x;
        ay += w * f.y;
    }
    ax = ax >= 0.f ? ax : 0.01f * ax;
    ay = ay >= 0.f ? ay : 0.01f * ay;
    float ss = ax * ax + ay * ay;
#pragma unroll
    for (int o = 32; o > 0; o >>= 1) ss += __shfl_xor(ss, o);
    float inv = 1.f / fmaxf(sqrtf(ss), 1e-12f);
    *(float2*)(enc_out + (size_t)row * 128 + lane * 2) = make_float2(ax * inv, ay * inv);
}

// ---------------- attention per (session, head); accumulates mean over L ----------------

__global__ __launch_bounds__(64) void attn_kernel(const float* __restrict__ qkv,
                                                  float* __restrict__ obar)
{
    const int b = blockIdx.x;
    const int h = blockIdx.y;
    const int l = threadIdx.x;  // 0..63
    __shared__ float ks[64][33];
    __shared__ float vs[64][33];
    __shared__ float os[64][33];
    const float* base = qkv + (size_t)b * SEQL * 384;
    float q[32];
#pragma unroll
    for (int j0 = 0; j0 < 32; j0 += 4) {
        float4 qv = *(const float4*)(base + (size_t)l * 384 + h * 32 + j0);
        q[j0 + 0] = qv.x; q[j0 + 1] = qv.y; q[j0 + 2] = qv.z; q[j0 + 3] = qv.w;
        float4 kv = *(const float4*)(base + (size_t)l * 384 + 128 + h * 32 + j0);
        ks[l][j0 + 0] = kv.x; ks[l][j0 + 1] = kv.y; ks[l][j0 + 2] = kv.z; ks[l][j0 + 3] = kv.w;
        float4 vv = *(const float4*)(base + (size_t)l * 384 + 256 + h * 32 + j0);
        vs[l][j0 + 0] = vv.x; vs[l][j0 + 1] = vv.y; vs[l][j0 + 2] = vv.z; vs[l][j0 + 3] = vv.w;
    }
    __syncthreads();

    const float scale = 0.17677669529663687f;  // 1/sqrt(32)
    float s[64];
    float mx = -1e30f;
#pragma unroll
    for (int m = 0; m < 64; ++m) {
        float acc = 0.f;
#pragma unroll
        for (int j = 0; j < 32; ++j) acc += q[j] * ks[m][j];
        acc *= scale;
        s[m] = acc;
        mx = fmaxf(mx, acc);
    }
    float sum = 0.f;
#pragma unroll
    for (int m = 0; m < 64; ++m) { float e = __expf(s[m] - mx); s[m] = e; sum += e; }
    float inv = 1.f / sum;
    float o[32];
#pragma unroll
    for (int j = 0; j < 32; ++j) o[j] = 0.f;
#pragma unroll
    for (int m = 0; m < 64; ++m) {
        float p = s[m] * inv;
#pragma unroll
        for (int j = 0; j < 32; ++j) o[j] += p * vs[m][j];
    }
#pragma unroll
    for (int j = 0; j < 32; ++j) os[l][j] = o[j];
    __syncthreads();
    if (l < 32) {
        float acc = 0.f;
#pragma unroll
        for (int m = 0; m < 64; ++m) acc += os[m][l];
        obar[(size_t)b * 128 + h * 32 + l] = acc * (1.f / 64.f);
    }
}

// ---------------- epilogue: fp32 outputs ----------------

__global__ void finalize_kernel(const float* __restrict__ aggr, const float* __restrict__ enc,
                                const int* __restrict__ data_poi, float* __restrict__ out)
{
    int i = blockIdx.x * blockDim.x + threadIdx.x;  // 0..131071
    if (i < BATCH * 128) {
        out[i] = aggr[i];
    } else {
        int j = i - BATCH * 128;
        int r = j >> 7, c = j & 127;
        out[i] = enc[(size_t)data_poi[r] * 128 + c];
    }
}

// ---------------- launch ----------------

extern "C" void kernel_launch(void* const* d_in, const int* in_sizes, int n_in,
                              void* d_out, int out_size, void* d_ws, size_t ws_size,
                              hipStream_t stream)
{
    const float* poi      = (const float*)d_in[0];
    const int*   edges    = (const int*)d_in[1];   // [2][NEDGE]
    const float* dvec     = (const float*)d_in[2];
    const int*   data_poi = (const int*)d_in[3];
    const int*   data_x   = (const int*)d_in[4];
    const float* lin_w    = (const float*)d_in[5];
    const float* lin_b    = (const float*)d_in[6];
    const float* inw      = (const float*)d_in[7];
    const float* inb      = (const float*)d_in[8];
    const float* outw     = (const float*)d_in[9];
    const float* outb     = (const float*)d_in[10];
    const int* e0 = edges;
    const int* e1 = edges + NEDGE;

    char* ws = (char*)d_ws;
    size_t off = 0;
    auto alloc = [&](size_t bytes) -> void* {
        void* p = ws + off;
        off = (off + bytes + 255) & ~(size_t)255;
        return p;
    };
    int*    counts = (int*)   alloc(NPOI * 4);
    int*    offs   = (int*)   alloc((NPOI + 1) * 4);
    int*    cursor = (int*)   alloc(NPOI * 4);
    float*  rd     = (float*) alloc(NPOI * 4);
    int*    bsum   = (int*)   alloc(SCAN_BLOCKS * 4);
    int*    bbase  = (int*)   alloc(SCAN_BLOCKS * 4);
    int2*   ew     = (int2*)  alloc((size_t)EAUG * 8);
    __half* hbuf   = (__half*)alloc((size_t)NPOI * 128 * 2);
    float*  enc    = (float*) alloc((size_t)NPOI * 128 * 4);
    float*  qkvb   = (float*) alloc((size_t)BATCH * SEQL * 384 * 4);
    float*  obar   = (float*) alloc((size_t)BATCH * 128 * 4);
    float*  aggr   = (float*) alloc((size_t)BATCH * 128 * 4);

    // graph structure
    init_counts_kernel<<<(NPOI + 255) / 256, 256, 0, stream>>>(counts);
    count_edges_kernel<<<(NEDGE + 255) / 256, 256, 0, stream>>>(e0, e1, counts);
    rsqrt_deg_kernel<<<(NPOI + 255) / 256, 256, 0, stream>>>(counts, rd);
    block_sum_kernel<<<SCAN_BLOCKS, 256, 0, stream>>>(counts, bsum);
    scan_mid_kernel<<<1, 256, 0, stream>>>(bsum, bbase);
    scan_chunk_kernel<<<SCAN_BLOCKS, 256, 0, stream>>>(counts, bbase, offs, cursor);
    fill_kernel<<<(EAUG + 255) / 256, 256, 0, stream>>>(e0, e1, dvec, rd, cursor, ew);

    // 2 graph-conv layers
    for (int l = 0; l < 2; ++l) {
        const float* a = (l == 0) ? poi : enc;
        gemm_bt_k128<__half><<<dim3((NPOI + 63) / 64, 2), 256, 0, stream>>>(
            a, nullptr, lin_w + (size_t)l * 128 * 128, lin_b + (size_t)l * 128,
            hbuf, NPOI, 128);
        aggregate_kernel<<<NPOI, 64, 0, stream>>>(hbuf, offs, ew, enc);
    }

    // attention
    gemm_bt_k128<float><<<dim3(BATCH * SEQL / 64, 6), 256, 0, stream>>>(
        enc, data_x, inw, inb, qkvb, BATCH * SEQL, 384);
    attn_kernel<<<dim3(BATCH, NHEADS), 64, 0, stream>>>(qkvb, obar);
    gemm_bt_k128<float><<<dim3(BATCH / 64, 2), 256, 0, stream>>>(
        obar, nullptr, outw, outb, aggr, BATCH, 128);

    finalize_kernel<<<(2 * BATCH * 128 + 255) / 256, 256, 0, stream>>>(
        aggr, enc, data_poi, (float*)d_out);
}

// Round 4
// 543.763 us; speedup vs baseline: 1.7538x; 1.0408x over previous
//
#include <hip/hip_runtime.h>
#include <hip/hip_fp16.h>
#include <type_traits>

#define NPOI 50000
#define EMB 128
#define NEDGE 800000
#define EAUG (2 * NEDGE + NPOI)
#define BATCH 512
#define SEQL 64
#define NHEADS 4
#define HDIM 32
#define SCAN_BLOCKS ((NPOI + 255) / 256)   // 196

typedef _Float16 half8 __attribute__((ext_vector_type(8)));
typedef _Float16 half4 __attribute__((ext_vector_type(4)));
typedef _Float16 half2t __attribute__((ext_vector_type(2)));
typedef float f32x4 __attribute__((ext_vector_type(4)));

// ---------------- fp32 -> fp16 convert ----------------

__global__ void cvt_kernel(const float* __restrict__ src, _Float16* __restrict__ dst, int n4) {
    int i = blockIdx.x * blockDim.x + threadIdx.x;
    if (i >= n4) return;
    float4 v = ((const float4*)src)[i];
    half4 h = { (_Float16)v.x, (_Float16)v.y, (_Float16)v.z, (_Float16)v.w };
    ((half4*)dst)[i] = h;
}

// ---------------- degree / CSR build ----------------

__global__ void init_counts_kernel(int* __restrict__ counts) {
    int i = blockIdx.x * blockDim.x + threadIdx.x;
    if (i < NPOI) counts[i] = 1;  // self loop
}

__global__ void count_edges_kernel(const int* __restrict__ e0, const int* __restrict__ e1,
                                   int* __restrict__ counts) {
    int e = blockIdx.x * blockDim.x + threadIdx.x;
    if (e < NEDGE) {
        atomicAdd(&counts[e0[e]], 1);
        atomicAdd(&counts[e1[e]], 1);
    }
}

__global__ void rsqrt_deg_kernel(const int* __restrict__ counts, float* __restrict__ rd) {
    int i = blockIdx.x * blockDim.x + threadIdx.x;
    if (i < NPOI) rd[i] = rsqrtf((float)counts[i]);
}

// coalesced hierarchical scan: block sums -> mid scan -> per-chunk scan
__global__ __launch_bounds__(256) void block_sum_kernel(const int* __restrict__ counts,
                                                        int* __restrict__ bsum) {
    __shared__ int sh[256];
    int i = blockIdx.x * 256 + threadIdx.x;
    sh[threadIdx.x] = (i < NPOI) ? counts[i] : 0;
    __syncthreads();
    for (int o = 128; o > 0; o >>= 1) {
        if (threadIdx.x < o) sh[threadIdx.x] += sh[threadIdx.x + o];
        __syncthreads();
    }
    if (threadIdx.x == 0) bsum[blockIdx.x] = sh[0];
}

__global__ __launch_bounds__(256) void scan_mid_kernel(const int* __restrict__ bsum,
                                                       int* __restrict__ bbase) {
    __shared__ int sh[256];
    int t = threadIdx.x;
    int v = (t < SCAN_BLOCKS) ? bsum[t] : 0;
    sh[t] = v;
    __syncthreads();
    for (int o = 1; o < 256; o <<= 1) {
        int u = (t >= o) ? sh[t - o] : 0;
        __syncthreads();
        sh[t] += u;
        __syncthreads();
    }
    if (t < SCAN_BLOCKS) bbase[t] = sh[t] - v;  // exclusive
}

__global__ __launch_bounds__(256) void scan_chunk_kernel(const int* __restrict__ counts,
                                                         const int* __restrict__ bbase,
                                                         int* __restrict__ offs,
                                                         int* __restrict__ cursor) {
    __shared__ int sh[256];
    int b = blockIdx.x, t = threadIdx.x;
    int i = b * 256 + t;
    int v = (i < NPOI) ? counts[i] : 0;
    sh[t] = v;
    __syncthreads();
    for (int o = 1; o < 256; o <<= 1) {
        int u = (t >= o) ? sh[t - o] : 0;
        __syncthreads();
        sh[t] += u;
        __syncthreads();
    }
    int excl = sh[t] - v + bbase[b];
    if (i < NPOI) {
        offs[i] = excl;
        cursor[i] = excl;
        if (i == NPOI - 1) offs[NPOI] = excl + v;
    }
}

// fill CSR with packed (dst, weight); fwd+rev share the (symmetric) weight
__global__ void fill_kernel(const int* __restrict__ e0, const int* __restrict__ e1,
                            const float* __restrict__ dv, const float* __restrict__ rd,
                            int* __restrict__ cursor, int2* __restrict__ ew) {
    int e = blockIdx.x * blockDim.x + threadIdx.x;
    if (e < NEDGE) {
        int s = e0[e], d = e1[e];
        float dist = dv[e];
        float w = rd[s] * rd[d] * expf(-dist * dist);
        int wb = __float_as_int(w);
        int ps = atomicAdd(&cursor[s], 1);
        ew[ps] = make_int2(d, wb);
        int pd = atomicAdd(&cursor[d], 1);
        ew[pd] = make_int2(s, wb);
    } else if (e < NEDGE + NPOI) {
        int s = e - NEDGE;
        float r = rd[s];
        int p = atomicAdd(&cursor[s], 1);
        ew[p] = make_int2(s, __float_as_int(r * r));
    }
}

// ---------------- fp16 MFMA GEMM: C[M,N] = A(gathered)[M,128] @ B[N,128]^T + bias ----------------
// 64x64 block tile, 4 waves, wave w covers cols [w*16, w*16+16), K=128 in 4 steps of 32.
// A-frag: A[m=lane&15][k=quad*8+j]; C/D: row=quad*4+reg, col=lane&15 (m89-verified layout).

template <typename OutT>
__global__ __launch_bounds__(256) void gemm_mfma_f16(
    const _Float16* __restrict__ A, const int* __restrict__ gidx,
    const _Float16* __restrict__ B, const float* __restrict__ bias,
    OutT* __restrict__ C, int M, int N)
{
    __shared__ _Float16 Asl[64][136];  // +8 halves pad: perfect bank spread for ds_read_b128
    __shared__ _Float16 Bsl[64][136];
    const int tid = threadIdx.x;
    const int n0 = blockIdx.x * 64;
    const int m0 = blockIdx.y * 64;

#pragma unroll
    for (int i = 0; i < 4; ++i) {
        int u = i * 256 + tid;
        int r = u >> 4;          // 0..63
        int c = u & 15;          // 16B chunk
        int row = m0 + r;
        int ar = (row < M) ? (gidx ? gidx[row] : row) : 0;
        *(float4*)&Asl[r][c * 8] = *(const float4*)(A + (size_t)ar * 128 + c * 8);
        *(float4*)&Bsl[r][c * 8] = *(const float4*)(B + (size_t)(n0 + r) * 128 + c * 8);
    }
    __syncthreads();

    const int wave = tid >> 6;
    const int lane = tid & 63;
    const int l15 = lane & 15;
    const int quad = lane >> 4;

    f32x4 acc[4];
#pragma unroll
    for (int mt = 0; mt < 4; ++mt) acc[mt] = (f32x4){0.f, 0.f, 0.f, 0.f};

#pragma unroll
    for (int ks = 0; ks < 4; ++ks) {
        half8 bfrag = *(const half8*)&Bsl[wave * 16 + l15][quad * 8 + ks * 32];
#pragma unroll
        for (int mt = 0; mt < 4; ++mt) {
            half8 afrag = *(const half8*)&Asl[mt * 16 + l15][quad * 8 + ks * 32];
            acc[mt] = __builtin_amdgcn_mfma_f32_16x16x32_f16(afrag, bfrag, acc[mt], 0, 0, 0);
        }
    }

    int col = n0 + wave * 16 + l15;
    float bv = bias[col];
#pragma unroll
    for (int mt = 0; mt < 4; ++mt) {
#pragma unroll
        for (int r = 0; r < 4; ++r) {
            int m = m0 + mt * 16 + quad * 4 + r;
            if (m < M) {
                float v = acc[mt][r] + bv;
                if constexpr (std::is_same<OutT, _Float16>::value)
                    C[(size_t)m * N + col] = (_Float16)v;
                else
                    C[(size_t)m * N + col] = v;
            }
        }
    }
}

// ---------------- fp32 vector GEMM (tiny, for obar @ out_proj) ----------------

__global__ __launch_bounds__(256) void gemm_bt_k128(
    const float* __restrict__ A, const float* __restrict__ B, const float* __restrict__ bias,
    float* __restrict__ C, int M, int N)
{
    __shared__ float As[128][64];
    __shared__ float Bs[128][64];
    const int tid = threadIdx.x;
    const int m0 = blockIdx.x * 64;
    const int n0 = blockIdx.y * 64;

#pragma unroll
    for (int i = 0; i < 8; ++i) {
        int f = i * 256 + tid;
        int r = f & 63;
        int kq = f >> 6;
        float4 av = make_float4(0.f, 0.f, 0.f, 0.f);
        int gm = m0 + r;
        if (gm < M) av = *(const float4*)(A + (size_t)gm * 128 + kq * 4);
        As[kq * 4 + 0][r] = av.x; As[kq * 4 + 1][r] = av.y;
        As[kq * 4 + 2][r] = av.z; As[kq * 4 + 3][r] = av.w;
        float4 bv = *(const float4*)(B + (size_t)(n0 + r) * 128 + kq * 4);
        Bs[kq * 4 + 0][r] = bv.x; Bs[kq * 4 + 1][r] = bv.y;
        Bs[kq * 4 + 2][r] = bv.z; Bs[kq * 4 + 3][r] = bv.w;
    }
    __syncthreads();

    const int tx = tid & 15;
    const int ty = tid >> 4;
    float acc[4][4];
#pragma unroll
    for (int i = 0; i < 4; ++i)
#pragma unroll
        for (int j = 0; j < 4; ++j) acc[i][j] = 0.f;

#pragma unroll 8
    for (int k = 0; k < 128; ++k) {
        float a4[4], b4[4];
        *(float4*)a4 = *(const float4*)&As[k][ty * 4];
        *(float4*)b4 = *(const float4*)&Bs[k][tx * 4];
#pragma unroll
        for (int i = 0; i < 4; ++i)
#pragma unroll
            for (int j = 0; j < 4; ++j) acc[i][j] += a4[i] * b4[j];
    }

#pragma unroll
    for (int i = 0; i < 4; ++i) {
        int gm = m0 + ty * 4 + i;
        if (gm >= M) continue;
        int gn = n0 + tx * 4;
        float4 o;
        o.x = acc[i][0] + bias[gn + 0];
        o.y = acc[i][1] + bias[gn + 1];
        o.z = acc[i][2] + bias[gn + 2];
        o.w = acc[i][3] + bias[gn + 3];
        *(float4*)(C + (size_t)gm * N + gn) = o;
    }
}

// ---------------- CSR aggregate + leaky-relu + L2 normalize ----------------
// one wave per row; h fp16; writes fp32 enc and fp16 enc_h

__global__ __launch_bounds__(64) void aggregate_kernel(
    const _Float16* __restrict__ h, const int* __restrict__ offs,
    const int2* __restrict__ ew, float* __restrict__ enc_out,
    _Float16* __restrict__ enc_h)
{
    const int row = blockIdx.x;
    const int lane = threadIdx.x;  // cols 2*lane, 2*lane+1
    const int beg = offs[row];
    const int end = offs[row + 1];
    float ax = 0.f, ay = 0.f;
#pragma unroll 2
    for (int e = beg; e < end; ++e) {
        int2 p = ew[e];
        float w = __int_as_float(p.y);
        half2t hv = *(const half2t*)(h + (size_t)p.x * 128 + lane * 2);
        ax += w * (float)hv[0];
        ay += w * (float)hv[1];
    }
    ax = ax >= 0.f ? ax : 0.01f * ax;
    ay = ay >= 0.f ? ay : 0.01f * ay;
    float ss = ax * ax + ay * ay;
#pragma unroll
    for (int o = 32; o > 0; o >>= 1) ss += __shfl_xor(ss, o);
    float inv = 1.f / fmaxf(sqrtf(ss), 1e-12f);
    float ex = ax * inv, ey = ay * inv;
    *(float2*)(enc_out + (size_t)row * 128 + lane * 2) = make_float2(ex, ey);
    half2t hv = { (_Float16)ex, (_Float16)ey };
    *(half2t*)(enc_h + (size_t)row * 128 + lane * 2) = hv;
}

// ---------------- attention per (session, head) ----------------

__global__ __launch_bounds__(64) void attn_kernel(const float* __restrict__ qkv,
                                                  float* __restrict__ obar)
{
    const int b = blockIdx.x;
    const int h = blockIdx.y;
    const int l = threadIdx.x;
    __shared__ float ks[64][33];
    __shared__ float vs[64][33];
    __shared__ float os[64][33];
    const float* base = qkv + (size_t)b * SEQL * 384;
    float q[32];
#pragma unroll
    for (int j0 = 0; j0 < 32; j0 += 4) {
        float4 qv = *(const float4*)(base + (size_t)l * 384 + h * 32 + j0);
        q[j0 + 0] = qv.x; q[j0 + 1] = qv.y; q[j0 + 2] = qv.z; q[j0 + 3] = qv.w;
        float4 kv = *(const float4*)(base + (size_t)l * 384 + 128 + h * 32 + j0);
        ks[l][j0 + 0] = kv.x; ks[l][j0 + 1] = kv.y; ks[l][j0 + 2] = kv.z; ks[l][j0 + 3] = kv.w;
        float4 vv = *(const float4*)(base + (size_t)l * 384 + 256 + h * 32 + j0);
        vs[l][j0 + 0] = vv.x; vs[l][j0 + 1] = vv.y; vs[l][j0 + 2] = vv.z; vs[l][j0 + 3] = vv.w;
    }
    __syncthreads();

    const float scale = 0.17677669529663687f;  // 1/sqrt(32)
    float s[64];
    float mx = -1e30f;
#pragma unroll
    for (int m = 0; m < 64; ++m) {
        float acc = 0.f;
#pragma unroll
        for (int j = 0; j < 32; ++j) acc += q[j] * ks[m][j];
        acc *= scale;
        s[m] = acc;
        mx = fmaxf(mx, acc);
    }
    float sum = 0.f;
#pragma unroll
    for (int m = 0; m < 64; ++m) { float e = __expf(s[m] - mx); s[m] = e; sum += e; }
    float inv = 1.f / sum;
    float o[32];
#pragma unroll
    for (int j = 0; j < 32; ++j) o[j] = 0.f;
#pragma unroll
    for (int m = 0; m < 64; ++m) {
        float p = s[m] * inv;
#pragma unroll
        for (int j = 0; j < 32; ++j) o[j] += p * vs[m][j];
    }
#pragma unroll
    for (int j = 0; j < 32; ++j) os[l][j] = o[j];
    __syncthreads();
    if (l < 32) {
        float acc = 0.f;
#pragma unroll
        for (int m = 0; m < 64; ++m) acc += os[m][l];
        obar[(size_t)b * 128 + h * 32 + l] = acc * (1.f / 64.f);
    }
}

// ---------------- epilogue ----------------

__global__ void finalize_kernel(const float* __restrict__ aggr, const float* __restrict__ enc,
                                const int* __restrict__ data_poi, float* __restrict__ out)
{
    int i = blockIdx.x * blockDim.x + threadIdx.x;
    if (i < BATCH * 128) {
        out[i] = aggr[i];
    } else {
        int j = i - BATCH * 128;
        int r = j >> 7, c = j & 127;
        out[i] = enc[(size_t)data_poi[r] * 128 + c];
    }
}

// ---------------- launch ----------------

extern "C" void kernel_launch(void* const* d_in, const int* in_sizes, int n_in,
                              void* d_out, int out_size, void* d_ws, size_t ws_size,
                              hipStream_t stream)
{
    const float* poi      = (const float*)d_in[0];
    const int*   edges    = (const int*)d_in[1];
    const float* dvec     = (const float*)d_in[2];
    const int*   data_poi = (const int*)d_in[3];
    const int*   data_x   = (const int*)d_in[4];
    const float* lin_w    = (const float*)d_in[5];
    const float* lin_b    = (const float*)d_in[6];
    const float* inw      = (const float*)d_in[7];
    const float* inb      = (const float*)d_in[8];
    const float* outw     = (const float*)d_in[9];
    const float* outb     = (const float*)d_in[10];
    const int* e0 = edges;
    const int* e1 = edges + NEDGE;

    char* ws = (char*)d_ws;
    size_t off = 0;
    auto alloc = [&](size_t bytes) -> void* {
        void* p = ws + off;
        off = (off + bytes + 255) & ~(size_t)255;
        return p;
    };
    int*      counts = (int*)     alloc(NPOI * 4);
    int*      offs   = (int*)     alloc((NPOI + 1) * 4);
    int*      cursor = (int*)     alloc(NPOI * 4);
    float*    rd     = (float*)   alloc(NPOI * 4);
    int*      bsum   = (int*)     alloc(SCAN_BLOCKS * 4);
    int*      bbase  = (int*)     alloc(SCAN_BLOCKS * 4);
    int2*     ew     = (int2*)    alloc((size_t)EAUG * 8);
    float*    enc    = (float*)   alloc((size_t)NPOI * 128 * 4);
    _Float16* enc_h  = (_Float16*)alloc((size_t)NPOI * 128 * 2);
    _Float16* linw_h = (_Float16*)alloc((size_t)2 * 128 * 128 * 2);
    _Float16* inw_h  = (_Float16*)alloc((size_t)384 * 128 * 2);
    float*    qkvb   = (float*)   alloc((size_t)BATCH * SEQL * 384 * 4);
    float*    obar   = (float*)   alloc((size_t)BATCH * 128 * 4);
    float*    aggr   = (float*)   alloc((size_t)BATCH * 128 * 4);
    // aliases inside qkvb's region: poi_h/hbuf dead before qkv gemm writes qkvb
    _Float16* poi_h  = (_Float16*)qkvb;                              // 12.8 MB
    _Float16* hbuf   = (_Float16*)((char*)qkvb + 16 * 1024 * 1024);  // 12.8 MB

    // fp16 pre-conversions
    cvt_kernel<<<(NPOI * 128 / 4 + 255) / 256, 256, 0, stream>>>(poi, poi_h, NPOI * 128 / 4);
    cvt_kernel<<<(2 * 128 * 128 / 4 + 255) / 256, 256, 0, stream>>>(lin_w, linw_h, 2 * 128 * 128 / 4);
    cvt_kernel<<<(384 * 128 / 4 + 255) / 256, 256, 0, stream>>>(inw, inw_h, 384 * 128 / 4);

    // graph structure
    init_counts_kernel<<<(NPOI + 255) / 256, 256, 0, stream>>>(counts);
    count_edges_kernel<<<(NEDGE + 255) / 256, 256, 0, stream>>>(e0, e1, counts);
    rsqrt_deg_kernel<<<(NPOI + 255) / 256, 256, 0, stream>>>(counts, rd);
    block_sum_kernel<<<SCAN_BLOCKS, 256, 0, stream>>>(counts, bsum);
    scan_mid_kernel<<<1, 256, 0, stream>>>(bsum, bbase);
    scan_chunk_kernel<<<SCAN_BLOCKS, 256, 0, stream>>>(counts, bbase, offs, cursor);
    fill_kernel<<<(NEDGE + NPOI + 255) / 256, 256, 0, stream>>>(e0, e1, dvec, rd, cursor, ew);

    // 2 graph-conv layers (MFMA fp16 GEMM + gather-aggregate)
    gemm_mfma_f16<_Float16><<<dim3(2, (NPOI + 63) / 64), 256, 0, stream>>>(
        poi_h, nullptr, linw_h, lin_b, hbuf, NPOI, 128);
    aggregate_kernel<<<NPOI, 64, 0, stream>>>(hbuf, offs, ew, enc, enc_h);
    gemm_mfma_f16<_Float16><<<dim3(2, (NPOI + 63) / 64), 256, 0, stream>>>(
        enc_h, nullptr, linw_h + 128 * 128, lin_b + 128, hbuf, NPOI, 128);
    aggregate_kernel<<<NPOI, 64, 0, stream>>>(hbuf, offs, ew, enc, enc_h);

    // attention
    gemm_mfma_f16<float><<<dim3(6, BATCH * SEQL / 64), 256, 0, stream>>>(
        enc_h, data_x, inw_h, inb, qkvb, BATCH * SEQL, 384);
    attn_kernel<<<dim3(BATCH, NHEADS), 64, 0, stream>>>(qkvb, obar);
    gemm_bt_k128<<<dim3(BATCH / 64, 2), 256, 0, stream>>>(obar, outw, outb, aggr, BATCH, 128);

    finalize_kernel<<<(2 * BATCH * 128 + 255) / 256, 256, 0, stream>>>(
        aggr, enc, data_poi, (float*)d_out);
}

// Round 5
// 460.510 us; speedup vs baseline: 2.0708x; 1.1808x over previous
//
#include <hip/hip_runtime.h>
#include <hip/hip_fp16.h>
#include <type_traits>

#define NPOI 50000
#define EMB 128
#define NEDGE 800000
#define EAUG (2 * NEDGE + NPOI)
#define BATCH 512
#define SEQL 64
#define NHEADS 4
#define HDIM 32
#define SCAN_BLOCKS ((NPOI + 255) / 256)   // 196

typedef _Float16 half8 __attribute__((ext_vector_type(8)));
typedef _Float16 half4 __attribute__((ext_vector_type(4)));
typedef _Float16 half2t __attribute__((ext_vector_type(2)));
typedef float f32x4 __attribute__((ext_vector_type(4)));

union HBits { _Float16 h; unsigned short u; };

// ---------------- fused fp32 -> fp16 convert (poi, lin_w, in_proj_w) ----------------

#define N4_POI (NPOI * 128 / 4)      // 1600000
#define N4_LIN (2 * 128 * 128 / 4)   // 8192
#define N4_INW (384 * 128 / 4)       // 12288

__global__ void cvt_all_kernel(const float* __restrict__ poi, const float* __restrict__ linw,
                               const float* __restrict__ inw,
                               _Float16* __restrict__ poi_h, _Float16* __restrict__ linw_h,
                               _Float16* __restrict__ inw_h) {
    int i = blockIdx.x * blockDim.x + threadIdx.x;
    const float* src; _Float16* dst; int j = i;
    if (i < N4_POI) { src = poi; dst = poi_h; }
    else if (i < N4_POI + N4_LIN) { j = i - N4_POI; src = linw; dst = linw_h; }
    else if (i < N4_POI + N4_LIN + N4_INW) { j = i - N4_POI - N4_LIN; src = inw; dst = inw_h; }
    else return;
    float4 v = ((const float4*)src)[j];
    half4 h = { (_Float16)v.x, (_Float16)v.y, (_Float16)v.z, (_Float16)v.w };
    ((half4*)dst)[j] = h;
}

// ---------------- degree / CSR build (deg = counts + 1; counts memset to 0) ----------------

__global__ void count_edges_kernel(const int* __restrict__ e0, const int* __restrict__ e1,
                                   int* __restrict__ counts) {
    int e = blockIdx.x * blockDim.x + threadIdx.x;
    if (e < NEDGE) {
        atomicAdd(&counts[e0[e]], 1);
        atomicAdd(&counts[e1[e]], 1);
    }
}

__global__ __launch_bounds__(256) void block_sum_kernel(const int* __restrict__ counts,
                                                        int* __restrict__ bsum) {
    __shared__ int sh[256];
    int i = blockIdx.x * 256 + threadIdx.x;
    sh[threadIdx.x] = (i < NPOI) ? (counts[i] + 1) : 0;   // +1 self loop
    __syncthreads();
    for (int o = 128; o > 0; o >>= 1) {
        if (threadIdx.x < o) sh[threadIdx.x] += sh[threadIdx.x + o];
        __syncthreads();
    }
    if (threadIdx.x == 0) bsum[blockIdx.x] = sh[0];
}

// fused mid-scan + chunk-scan: each block redundantly scans the 196 block sums in LDS
__global__ __launch_bounds__(256) void scan_chunk_kernel(const int* __restrict__ counts,
                                                         const int* __restrict__ bsum,
                                                         int* __restrict__ offs,
                                                         int* __restrict__ cursor) {
    __shared__ int shb[256];
    __shared__ int sh[256];
    __shared__ int base_sh;
    int b = blockIdx.x, t = threadIdx.x;
    shb[t] = (t < SCAN_BLOCKS) ? bsum[t] : 0;
    __syncthreads();
    // block base = sum of shb[0..b-1], cooperative
    int partial = 0;
    for (int j = t; j < b; j += 256) partial += shb[j];
    sh[t] = partial;
    __syncthreads();
    for (int o = 128; o > 0; o >>= 1) {
        if (t < o) sh[t] += sh[t + o];
        __syncthreads();
    }
    if (t == 0) base_sh = sh[0];
    __syncthreads();
    int bbase = base_sh;
    __syncthreads();
    // inclusive scan of this chunk's (counts+1)
    int i = b * 256 + t;
    int v = (i < NPOI) ? (counts[i] + 1) : 0;
    sh[t] = v;
    __syncthreads();
    for (int o = 1; o < 256; o <<= 1) {
        int u = (t >= o) ? sh[t - o] : 0;
        __syncthreads();
        sh[t] += u;
        __syncthreads();
    }
    int excl = sh[t] - v + bbase;
    if (i < NPOI) {
        offs[i] = excl;
        cursor[i] = excl;
        if (i == NPOI - 1) offs[NPOI] = excl + v;
    }
}

// fill CSR with packed 4B entries (dst<<16 | fp16 weight); fwd+rev share symmetric weight
__global__ void fill_kernel(const int* __restrict__ e0, const int* __restrict__ e1,
                            const float* __restrict__ dv, const int* __restrict__ counts,
                            int* __restrict__ cursor, unsigned* __restrict__ ew) {
    int e = blockIdx.x * blockDim.x + threadIdx.x;
    if (e < NEDGE) {
        int s = e0[e], d = e1[e];
        float dist = dv[e];
        float degp = (float)(counts[s] + 1) * (float)(counts[d] + 1);
        float w = rsqrtf(degp) * expf(-dist * dist);
        HBits cv; cv.h = (_Float16)w;
        int ps = atomicAdd(&cursor[s], 1);
        ew[ps] = ((unsigned)d << 16) | cv.u;
        int pd = atomicAdd(&cursor[d], 1);
        ew[pd] = ((unsigned)s << 16) | cv.u;
    } else if (e < NEDGE + NPOI) {
        int s = e - NEDGE;
        float w = 1.0f / (float)(counts[s] + 1);
        HBits cv; cv.h = (_Float16)w;
        int p = atomicAdd(&cursor[s], 1);
        ew[p] = ((unsigned)s << 16) | cv.u;
    }
}

// ---------------- fp16 MFMA GEMM: C[M,N] = A(gathered)[M,128] @ B[N,128]^T + bias ----------------

template <typename OutT>
__global__ __launch_bounds__(256) void gemm_mfma_f16(
    const _Float16* __restrict__ A, const int* __restrict__ gidx,
    const _Float16* __restrict__ B, const float* __restrict__ bias,
    OutT* __restrict__ C, int M, int N)
{
    __shared__ _Float16 Asl[64][136];
    __shared__ _Float16 Bsl[64][136];
    const int tid = threadIdx.x;
    const int n0 = blockIdx.x * 64;
    const int m0 = blockIdx.y * 64;

#pragma unroll
    for (int i = 0; i < 4; ++i) {
        int u = i * 256 + tid;
        int r = u >> 4;
        int c = u & 15;
        int row = m0 + r;
        int ar = (row < M) ? (gidx ? gidx[row] : row) : 0;
        *(float4*)&Asl[r][c * 8] = *(const float4*)(A + (size_t)ar * 128 + c * 8);
        *(float4*)&Bsl[r][c * 8] = *(const float4*)(B + (size_t)(n0 + r) * 128 + c * 8);
    }
    __syncthreads();

    const int wave = tid >> 6;
    const int lane = tid & 63;
    const int l15 = lane & 15;
    const int quad = lane >> 4;

    f32x4 acc[4];
#pragma unroll
    for (int mt = 0; mt < 4; ++mt) acc[mt] = (f32x4){0.f, 0.f, 0.f, 0.f};

#pragma unroll
    for (int ks = 0; ks < 4; ++ks) {
        half8 bfrag = *(const half8*)&Bsl[wave * 16 + l15][quad * 8 + ks * 32];
#pragma unroll
        for (int mt = 0; mt < 4; ++mt) {
            half8 afrag = *(const half8*)&Asl[mt * 16 + l15][quad * 8 + ks * 32];
            acc[mt] = __builtin_amdgcn_mfma_f32_16x16x32_f16(afrag, bfrag, acc[mt], 0, 0, 0);
        }
    }

    int col = n0 + wave * 16 + l15;
    float bv = bias[col];
#pragma unroll
    for (int mt = 0; mt < 4; ++mt) {
#pragma unroll
        for (int r = 0; r < 4; ++r) {
            int m = m0 + mt * 16 + quad * 4 + r;
            if (m < M) {
                float v = acc[mt][r] + bv;
                if constexpr (std::is_same<OutT, _Float16>::value)
                    C[(size_t)m * N + col] = (_Float16)v;
                else
                    C[(size_t)m * N + col] = v;
            }
        }
    }
}

// ---------------- CSR aggregate + leaky-relu + L2 normalize ----------------

__global__ __launch_bounds__(64) void aggregate_kernel(
    const _Float16* __restrict__ h, const int* __restrict__ offs,
    const unsigned* __restrict__ ew, float* __restrict__ enc_out,
    _Float16* __restrict__ enc_h)
{
    const int row = blockIdx.x;
    const int lane = threadIdx.x;  // cols 2*lane, 2*lane+1
    const int beg = offs[row];
    const int end = offs[row + 1];
    float ax = 0.f, ay = 0.f;
#pragma unroll 4
    for (int e = beg; e < end; ++e) {
        unsigned p = ew[e];                    // uniform -> scalar load
        HBits cv; cv.u = (unsigned short)(p & 0xffffu);
        float w = (float)cv.h;
        int d = p >> 16;
        half2t hv = *(const half2t*)(h + (size_t)d * 128 + lane * 2);
        ax += w * (float)hv[0];
        ay += w * (float)hv[1];
    }
    ax = ax >= 0.f ? ax : 0.01f * ax;
    ay = ay >= 0.f ? ay : 0.01f * ay;
    float ss = ax * ax + ay * ay;
#pragma unroll
    for (int o = 32; o > 0; o >>= 1) ss += __shfl_xor(ss, o);
    float inv = 1.f / fmaxf(sqrtf(ss), 1e-12f);
    float ex = ax * inv, ey = ay * inv;
    *(float2*)(enc_out + (size_t)row * 128 + lane * 2) = make_float2(ex, ey);
    half2t hv = { (_Float16)ex, (_Float16)ey };
    *(half2t*)(enc_h + (size_t)row * 128 + lane * 2) = hv;
}

// ---------------- fused attention + mean + out_proj; block = session, wave = head ----------------
// online softmax (no s[64] -> no spills); mean over L before out_proj (linearity-exact)

__global__ __launch_bounds__(256) void attn_fused_kernel(
    const float* __restrict__ qkv, const float* __restrict__ outw,
    const float* __restrict__ outb, float* __restrict__ out)
{
    const int b = blockIdx.x;
    const int h = threadIdx.x >> 6;   // head
    const int l = threadIdx.x & 63;   // query row
    __shared__ float ks[NHEADS][64][33];
    __shared__ float vs[NHEADS][64][33];
    __shared__ float ob[128];
    const float* base = qkv + (size_t)b * SEQL * 384;
    const float scale = 0.17677669529663687f;  // 1/sqrt(32)
    float q[32];
#pragma unroll
    for (int j0 = 0; j0 < 32; j0 += 4) {
        float4 qv = *(const float4*)(base + (size_t)l * 384 + h * 32 + j0);
        q[j0 + 0] = qv.x * scale; q[j0 + 1] = qv.y * scale;
        q[j0 + 2] = qv.z * scale; q[j0 + 3] = qv.w * scale;
        float4 kv = *(const float4*)(base + (size_t)l * 384 + 128 + h * 32 + j0);
        ks[h][l][j0 + 0] = kv.x; ks[h][l][j0 + 1] = kv.y;
        ks[h][l][j0 + 2] = kv.z; ks[h][l][j0 + 3] = kv.w;
        float4 vv = *(const float4*)(base + (size_t)l * 384 + 256 + h * 32 + j0);
        vs[h][l][j0 + 0] = vv.x; vs[h][l][j0 + 1] = vv.y;
        vs[h][l][j0 + 2] = vv.z; vs[h][l][j0 + 3] = vv.w;
    }
    __syncthreads();

    float mx = -1e30f, sum = 0.f;
    float o[32];
#pragma unroll
    for (int j = 0; j < 32; ++j) o[j] = 0.f;
#pragma unroll 2
    for (int m = 0; m < 64; ++m) {
        float s = 0.f;
#pragma unroll
        for (int j = 0; j < 32; ++j) s += q[j] * ks[h][m][j];   // broadcast reads
        float nm = fmaxf(mx, s);
        float alpha = __expf(mx - nm);
        float p = __expf(s - nm);
        sum = sum * alpha + p;
        mx = nm;
#pragma unroll
        for (int j = 0; j < 32; ++j) o[j] = o[j] * alpha + p * vs[h][m][j];
    }
    float inv = 1.f / sum;
    __syncthreads();                 // everyone done with ks -> reuse as os
    float (*os)[64][33] = ks;
#pragma unroll
    for (int j = 0; j < 32; ++j) os[h][l][j] = o[j] * inv;
    __syncthreads();

    int t = threadIdx.x;
    if (t < 128) {
        int h2 = t >> 5, j = t & 31;
        float s = 0.f;
#pragma unroll
        for (int m = 0; m < 64; ++m) s += os[h2][m][j];
        ob[t] = s * (1.f / 64.f);
    }
    __syncthreads();
    if (t < 128) {
        float val = outb[t];
        const float* wrow = outw + (size_t)t * 128;
#pragma unroll 8
        for (int k4 = 0; k4 < 32; ++k4) {
            float4 wv = *(const float4*)(wrow + k4 * 4);
            val += wv.x * ob[k4 * 4] + wv.y * ob[k4 * 4 + 1]
                 + wv.z * ob[k4 * 4 + 2] + wv.w * ob[k4 * 4 + 3];
        }
        out[(size_t)b * 128 + t] = val;
    }
}

// ---------------- tar_embed gather ----------------

__global__ void tar_kernel(const float* __restrict__ enc, const int* __restrict__ data_poi,
                           float* __restrict__ out)
{
    int i = blockIdx.x * blockDim.x + threadIdx.x;
    if (i >= BATCH * 128) return;
    int r = i >> 7, c = i & 127;
    out[i] = enc[(size_t)data_poi[r] * 128 + c];
}

// ---------------- launch ----------------

extern "C" void kernel_launch(void* const* d_in, const int* in_sizes, int n_in,
                              void* d_out, int out_size, void* d_ws, size_t ws_size,
                              hipStream_t stream)
{
    const float* poi      = (const float*)d_in[0];
    const int*   edges    = (const int*)d_in[1];
    const float* dvec     = (const float*)d_in[2];
    const int*   data_poi = (const int*)d_in[3];
    const int*   data_x   = (const int*)d_in[4];
    const float* lin_w    = (const float*)d_in[5];
    const float* lin_b    = (const float*)d_in[6];
    const float* inw      = (const float*)d_in[7];
    const float* inb      = (const float*)d_in[8];
    const float* outw     = (const float*)d_in[9];
    const float* outb     = (const float*)d_in[10];
    const int* e0 = edges;
    const int* e1 = edges + NEDGE;

    char* ws = (char*)d_ws;
    size_t off = 0;
    auto alloc = [&](size_t bytes) -> void* {
        void* p = ws + off;
        off = (off + bytes + 255) & ~(size_t)255;
        return p;
    };
    int*      counts = (int*)     alloc(NPOI * 4);
    int*      offs   = (int*)     alloc((NPOI + 1) * 4);
    int*      cursor = (int*)     alloc(NPOI * 4);
    int*      bsum   = (int*)     alloc(SCAN_BLOCKS * 4);
    unsigned* ew     = (unsigned*)alloc((size_t)EAUG * 4);
    float*    enc    = (float*)   alloc((size_t)NPOI * 128 * 4);
    _Float16* enc_h  = (_Float16*)alloc((size_t)NPOI * 128 * 2);
    _Float16* linw_h = (_Float16*)alloc((size_t)2 * 128 * 128 * 2);
    _Float16* inw_h  = (_Float16*)alloc((size_t)384 * 128 * 2);
    float*    qkvb   = (float*)   alloc((size_t)BATCH * SEQL * 384 * 4);
    // aliases inside qkvb's region: poi_h/hbuf dead before qkv gemm writes qkvb
    _Float16* poi_h  = (_Float16*)qkvb;                              // 12.8 MB
    _Float16* hbuf   = (_Float16*)((char*)qkvb + 16 * 1024 * 1024);  // 12.8 MB

    hipMemsetAsync(counts, 0, NPOI * 4, stream);

    cvt_all_kernel<<<(N4_POI + N4_LIN + N4_INW + 255) / 256, 256, 0, stream>>>(
        poi, lin_w, inw, poi_h, linw_h, inw_h);

    count_edges_kernel<<<(NEDGE + 255) / 256, 256, 0, stream>>>(e0, e1, counts);
    block_sum_kernel<<<SCAN_BLOCKS, 256, 0, stream>>>(counts, bsum);
    scan_chunk_kernel<<<SCAN_BLOCKS, 256, 0, stream>>>(counts, bsum, offs, cursor);
    fill_kernel<<<(NEDGE + NPOI + 255) / 256, 256, 0, stream>>>(e0, e1, dvec, counts, cursor, ew);

    // 2 graph-conv layers
    gemm_mfma_f16<_Float16><<<dim3(2, (NPOI + 63) / 64), 256, 0, stream>>>(
        poi_h, nullptr, linw_h, lin_b, hbuf, NPOI, 128);
    aggregate_kernel<<<NPOI, 64, 0, stream>>>(hbuf, offs, ew, enc, enc_h);
    gemm_mfma_f16<_Float16><<<dim3(2, (NPOI + 63) / 64), 256, 0, stream>>>(
        enc_h, nullptr, linw_h + 128 * 128, lin_b + 128, hbuf, NPOI, 128);
    aggregate_kernel<<<NPOI, 64, 0, stream>>>(hbuf, offs, ew, enc, enc_h);

    // attention (qkv gemm -> fused attn+mean+out_proj -> d_out)
    gemm_mfma_f16<float><<<dim3(6, BATCH * SEQL / 64), 256, 0, stream>>>(
        enc_h, data_x, inw_h, inb, qkvb, BATCH * SEQL, 384);
    attn_fused_kernel<<<BATCH, 256, 0, stream>>>(qkvb, outw, outb, (float*)d_out);

    tar_kernel<<<(BATCH * 128 + 255) / 256, 256, 0, stream>>>(
        enc, data_poi, (float*)d_out + BATCH * 128);
}

// Round 6
// 409.608 us; speedup vs baseline: 2.3282x; 1.1243x over previous
//
#include <hip/hip_runtime.h>
#include <hip/hip_fp16.h>
#include <type_traits>

#define NPOI 50000
#define EMB 128
#define NEDGE 800000
#define EAUG (2 * NEDGE + NPOI)
#define BATCH 512
#define SEQL 64
#define NHEADS 4
#define HDIM 32
#define SCAN_BLOCKS ((NPOI + 255) / 256)   // 196
#define NB SCAN_BLOCKS                      // 256-node buckets == scan chunks
#define P1_SLOTS (NEDGE + NPOI)             // 850000
#define P1_BLOCKS ((P1_SLOTS + 2047) / 2048)
#define BUCKET_CAP 10240                    // mean 8448, sigma ~90 -> 20-sigma margin

typedef _Float16 half8 __attribute__((ext_vector_type(8)));
typedef _Float16 half4 __attribute__((ext_vector_type(4)));
typedef _Float16 half2t __attribute__((ext_vector_type(2)));
typedef float f32x4 __attribute__((ext_vector_type(4)));

union HBits { _Float16 h; unsigned short u; };

// ---------------- fused fp32 -> fp16 convert (poi, lin_w, in_proj_w) ----------------

#define N4_POI (NPOI * 128 / 4)
#define N4_LIN (2 * 128 * 128 / 4)
#define N4_INW (384 * 128 / 4)

__global__ void cvt_all_kernel(const float* __restrict__ poi, const float* __restrict__ linw,
                               const float* __restrict__ inw,
                               _Float16* __restrict__ poi_h, _Float16* __restrict__ linw_h,
                               _Float16* __restrict__ inw_h) {
    int i = blockIdx.x * blockDim.x + threadIdx.x;
    const float* src; _Float16* dst; int j = i;
    if (i < N4_POI) { src = poi; dst = poi_h; }
    else if (i < N4_POI + N4_LIN) { j = i - N4_POI; src = linw; dst = linw_h; }
    else if (i < N4_POI + N4_LIN + N4_INW) { j = i - N4_POI - N4_LIN; src = inw; dst = inw_h; }
    else return;
    float4 v = ((const float4*)src)[j];
    half4 h = { (_Float16)v.x, (_Float16)v.y, (_Float16)v.z, (_Float16)v.w };
    ((half4*)dst)[j] = h;
}

// ---------------- degree (deg = counts + 1; counts memset to 0) ----------------

__global__ void count_edges_kernel(const int* __restrict__ e0, const int* __restrict__ e1,
                                   int* __restrict__ counts) {
    int e = blockIdx.x * blockDim.x + threadIdx.x;
    if (e < NEDGE) {
        atomicAdd(&counts[e0[e]], 1);
        atomicAdd(&counts[e1[e]], 1);
    }
}

__global__ __launch_bounds__(256) void block_sum_kernel(const int* __restrict__ counts,
                                                        int* __restrict__ bsum) {
    __shared__ int sh[256];
    int i = blockIdx.x * 256 + threadIdx.x;
    sh[threadIdx.x] = (i < NPOI) ? (counts[i] + 1) : 0;   // +1 self loop
    __syncthreads();
    for (int o = 128; o > 0; o >>= 1) {
        if (threadIdx.x < o) sh[threadIdx.x] += sh[threadIdx.x + o];
        __syncthreads();
    }
    if (threadIdx.x == 0) bsum[blockIdx.x] = sh[0];
}

// fused mid-scan + chunk-scan; also emits per-bucket base cursors (bucket == chunk)
__global__ __launch_bounds__(256) void scan_chunk_kernel(const int* __restrict__ counts,
                                                         const int* __restrict__ bsum,
                                                         int* __restrict__ offs,
                                                         int* __restrict__ bcur) {
    __shared__ int shb[256];
    __shared__ int sh[256];
    __shared__ int base_sh;
    int b = blockIdx.x, t = threadIdx.x;
    shb[t] = (t < SCAN_BLOCKS) ? bsum[t] : 0;
    __syncthreads();
    int partial = 0;
    for (int j = t; j < b; j += 256) partial += shb[j];
    sh[t] = partial;
    __syncthreads();
    for (int o = 128; o > 0; o >>= 1) {
        if (t < o) sh[t] += sh[t + o];
        __syncthreads();
    }
    if (t == 0) base_sh = sh[0];
    __syncthreads();
    int bbase = base_sh;
    __syncthreads();
    int i = b * 256 + t;
    int v = (i < NPOI) ? (counts[i] + 1) : 0;
    sh[t] = v;
    __syncthreads();
    for (int o = 1; o < 256; o <<= 1) {
        int u = (t >= o) ? sh[t - o] : 0;
        __syncthreads();
        sh[t] += u;
        __syncthreads();
    }
    int excl = sh[t] - v + bbase;
    if (i < NPOI) {
        offs[i] = excl;
        if (i == NPOI - 1) offs[NPOI] = excl + v;
    }
    if (t == 0) bcur[b] = bbase;   // bucket write cursor starts at bucket base
}

// ---------------- phase 1: LDS-buffered multisplit into bucket-grouped staging ----------------
// entry u64 = s(16) << 32 | d(16) << 16 | w(fp16). Writes land in ~21-entry contiguous runs.

__global__ __launch_bounds__(256) void partition_kernel(
    const int* __restrict__ e0, const int* __restrict__ e1,
    const float* __restrict__ dv, const int* __restrict__ counts,
    int* __restrict__ bcur, unsigned long long* __restrict__ staging)
{
    __shared__ unsigned long long stg[4096];
    __shared__ int lh[NB], lbase[NB], gb[NB];
    __shared__ int sc[256];
    const int t = threadIdx.x;
    const int blockBase = blockIdx.x * 2048;
    for (int j = t; j < NB; j += 256) lh[j] = 0;
    __syncthreads();

    unsigned long long vals[16];
    unsigned br[16];
#pragma unroll
    for (int i = 0; i < 8; ++i) {
        br[2 * i] = 0xFFFFFFFFu;
        br[2 * i + 1] = 0xFFFFFFFFu;
        int g = blockBase + i * 256 + t;
        if (g < NEDGE) {
            int s = e0[g], d = e1[g];
            float dist = dv[g];
            float w = rsqrtf((float)(counts[s] + 1) * (float)(counts[d] + 1)) * expf(-dist * dist);
            HBits cv; cv.h = (_Float16)w;
            vals[2 * i]     = ((unsigned long long)s << 32) | ((unsigned)d << 16) | cv.u;
            vals[2 * i + 1] = ((unsigned long long)d << 32) | ((unsigned)s << 16) | cv.u;
            int bs = s >> 8, bd = d >> 8;
            int rs = atomicAdd(&lh[bs], 1);
            int rd = atomicAdd(&lh[bd], 1);
            br[2 * i]     = ((unsigned)bs << 16) | (unsigned)rs;
            br[2 * i + 1] = ((unsigned)bd << 16) | (unsigned)rd;
        } else if (g < NEDGE + NPOI) {
            int s = g - NEDGE;
            float w = 1.0f / (float)(counts[s] + 1);
            HBits cv; cv.h = (_Float16)w;
            vals[2 * i] = ((unsigned long long)s << 32) | ((unsigned)s << 16) | cv.u;
            int bs = s >> 8;
            int rs = atomicAdd(&lh[bs], 1);
            br[2 * i] = ((unsigned)bs << 16) | (unsigned)rs;
        }
    }
    __syncthreads();
    // exclusive scan of lh; reserve global space per bucket
    sc[t] = (t < NB) ? lh[t] : 0;
    __syncthreads();
    for (int o = 1; o < 256; o <<= 1) {
        int u = (t >= o) ? sc[t - o] : 0;
        __syncthreads();
        sc[t] += u;
        __syncthreads();
    }
    if (t < NB) {
        lbase[t] = sc[t] - lh[t];
        gb[t] = (lh[t] > 0) ? atomicAdd(&bcur[t], lh[t]) : 0;
    }
    __syncthreads();
    // scatter into LDS staging, bucket-major
#pragma unroll
    for (int i = 0; i < 16; ++i) {
        if (br[i] != 0xFFFFFFFFu) {
            int b = br[i] >> 16, r = br[i] & 0xFFFF;
            stg[lbase[b] + r] = vals[i];
        }
    }
    __syncthreads();
    const int total = sc[255];
    for (int j = t; j < total; j += 256) {
        unsigned long long v = stg[j];
        int b = (int)(v >> 40);    // s >> 8
        staging[(size_t)gb[b] + (unsigned)(j - lbase[b])] = v;
    }
}

// ---------------- phase 2: per-bucket LDS counting sort -> final packed CSR ----------------

__global__ __launch_bounds__(256) void csr_sort_kernel(
    const unsigned long long* __restrict__ staging, const int* __restrict__ offs,
    unsigned* __restrict__ ew)
{
    const int k = blockIdx.x;
    const int node0 = k * 256;
    const int node1 = (node0 + 256 < NPOI) ? node0 + 256 : NPOI;
    const int beg = offs[node0];
    const int n = offs[node1] - beg;
    __shared__ unsigned outb[BUCKET_CAP];
    __shared__ int cnt[256], base2[256];
    const int t = threadIdx.x;
    cnt[t] = 0;
    __syncthreads();
    for (int j = t; j < n; j += 256)
        atomicAdd(&cnt[(int)(staging[beg + j] >> 32) & 255], 1);
    __syncthreads();
    int v = cnt[t];
    base2[t] = v;
    __syncthreads();
    for (int o = 1; o < 256; o <<= 1) {
        int u = (t >= o) ? base2[t - o] : 0;
        __syncthreads();
        base2[t] += u;
        __syncthreads();
    }
    int myexc = base2[t] - v;
    __syncthreads();
    base2[t] = myexc;
    cnt[t] = 0;
    __syncthreads();
    for (int j = t; j < n; j += 256) {
        unsigned long long e = staging[beg + j];
        int sl = (int)(e >> 32) & 255;
        int r = atomicAdd(&cnt[sl], 1);
        outb[base2[sl] + r] = (unsigned)e;   // (d<<16)|w16
    }
    __syncthreads();
    for (int j = t; j < n; j += 256) ew[beg + j] = outb[j];   // coalesced
}

// ---------------- fp16 MFMA GEMM: C[M,N] = A(gathered)[M,128] @ B[N,128]^T + bias ----------------

template <typename OutT>
__global__ __launch_bounds__(256) void gemm_mfma_f16(
    const _Float16* __restrict__ A, const int* __restrict__ gidx,
    const _Float16* __restrict__ B, const float* __restrict__ bias,
    OutT* __restrict__ C, int M, int N)
{
    __shared__ _Float16 Asl[64][136];
    __shared__ _Float16 Bsl[64][136];
    const int tid = threadIdx.x;
    const int n0 = blockIdx.x * 64;
    const int m0 = blockIdx.y * 64;

#pragma unroll
    for (int i = 0; i < 4; ++i) {
        int u = i * 256 + tid;
        int r = u >> 4;
        int c = u & 15;
        int row = m0 + r;
        int ar = (row < M) ? (gidx ? gidx[row] : row) : 0;
        *(float4*)&Asl[r][c * 8] = *(const float4*)(A + (size_t)ar * 128 + c * 8);
        *(float4*)&Bsl[r][c * 8] = *(const float4*)(B + (size_t)(n0 + r) * 128 + c * 8);
    }
    __syncthreads();

    const int wave = tid >> 6;
    const int lane = tid & 63;
    const int l15 = lane & 15;
    const int quad = lane >> 4;

    f32x4 acc[4];
#pragma unroll
    for (int mt = 0; mt < 4; ++mt) acc[mt] = (f32x4){0.f, 0.f, 0.f, 0.f};

#pragma unroll
    for (int ks = 0; ks < 4; ++ks) {
        half8 bfrag = *(const half8*)&Bsl[wave * 16 + l15][quad * 8 + ks * 32];
#pragma unroll
        for (int mt = 0; mt < 4; ++mt) {
            half8 afrag = *(const half8*)&Asl[mt * 16 + l15][quad * 8 + ks * 32];
            acc[mt] = __builtin_amdgcn_mfma_f32_16x16x32_f16(afrag, bfrag, acc[mt], 0, 0, 0);
        }
    }

    int col = n0 + wave * 16 + l15;
    float bv = bias[col];
#pragma unroll
    for (int mt = 0; mt < 4; ++mt) {
#pragma unroll
        for (int r = 0; r < 4; ++r) {
            int m = m0 + mt * 16 + quad * 4 + r;
            if (m < M) {
                float v = acc[mt][r] + bv;
                if constexpr (std::is_same<OutT, _Float16>::value)
                    C[(size_t)m * N + col] = (_Float16)v;
                else
                    C[(size_t)m * N + col] = v;
            }
        }
    }
}

// ---------------- CSR aggregate + leaky-relu + L2 normalize ----------------

__global__ __launch_bounds__(64) void aggregate_kernel(
    const _Float16* __restrict__ h, const int* __restrict__ offs,
    const unsigned* __restrict__ ew, float* __restrict__ enc_out,
    _Float16* __restrict__ enc_h)
{
    const int row = blockIdx.x;
    const int lane = threadIdx.x;  // cols 2*lane, 2*lane+1
    const int beg = offs[row];
    const int end = offs[row + 1];
    float ax = 0.f, ay = 0.f;
#pragma unroll 4
    for (int e = beg; e < end; ++e) {
        unsigned p = ew[e];
        HBits cv; cv.u = (unsigned short)(p & 0xffffu);
        float w = (float)cv.h;
        int d = p >> 16;
        half2t hv = *(const half2t*)(h + (size_t)d * 128 + lane * 2);
        ax += w * (float)hv[0];
        ay += w * (float)hv[1];
    }
    ax = ax >= 0.f ? ax : 0.01f * ax;
    ay = ay >= 0.f ? ay : 0.01f * ay;
    float ss = ax * ax + ay * ay;
#pragma unroll
    for (int o = 32; o > 0; o >>= 1) ss += __shfl_xor(ss, o);
    float inv = 1.f / fmaxf(sqrtf(ss), 1e-12f);
    float ex = ax * inv, ey = ay * inv;
    *(float2*)(enc_out + (size_t)row * 128 + lane * 2) = make_float2(ex, ey);
    half2t hv = { (_Float16)ex, (_Float16)ey };
    *(half2t*)(enc_h + (size_t)row * 128 + lane * 2) = hv;
}

// ---------------- fused attention + mean + out_proj ----------------

__global__ __launch_bounds__(256) void attn_fused_kernel(
    const float* __restrict__ qkv, const float* __restrict__ outw,
    const float* __restrict__ outb, float* __restrict__ out)
{
    const int b = blockIdx.x;
    const int h = threadIdx.x >> 6;
    const int l = threadIdx.x & 63;
    __shared__ float ks[NHEADS][64][33];
    __shared__ float vs[NHEADS][64][33];
    __shared__ float ob[128];
    const float* base = qkv + (size_t)b * SEQL * 384;
    const float scale = 0.17677669529663687f;
    float q[32];
#pragma unroll
    for (int j0 = 0; j0 < 32; j0 += 4) {
        float4 qv = *(const float4*)(base + (size_t)l * 384 + h * 32 + j0);
        q[j0 + 0] = qv.x * scale; q[j0 + 1] = qv.y * scale;
        q[j0 + 2] = qv.z * scale; q[j0 + 3] = qv.w * scale;
        float4 kv = *(const float4*)(base + (size_t)l * 384 + 128 + h * 32 + j0);
        ks[h][l][j0 + 0] = kv.x; ks[h][l][j0 + 1] = kv.y;
        ks[h][l][j0 + 2] = kv.z; ks[h][l][j0 + 3] = kv.w;
        float4 vv = *(const float4*)(base + (size_t)l * 384 + 256 + h * 32 + j0);
        vs[h][l][j0 + 0] = vv.x; vs[h][l][j0 + 1] = vv.y;
        vs[h][l][j0 + 2] = vv.z; vs[h][l][j0 + 3] = vv.w;
    }
    __syncthreads();

    float mx = -1e30f, sum = 0.f;
    float o[32];
#pragma unroll
    for (int j = 0; j < 32; ++j) o[j] = 0.f;
#pragma unroll 2
    for (int m = 0; m < 64; ++m) {
        float s = 0.f;
#pragma unroll
        for (int j = 0; j < 32; ++j) s += q[j] * ks[h][m][j];
        float nm = fmaxf(mx, s);
        float alpha = __expf(mx - nm);
        float p = __expf(s - nm);
        sum = sum * alpha + p;
        mx = nm;
#pragma unroll
        for (int j = 0; j < 32; ++j) o[j] = o[j] * alpha + p * vs[h][m][j];
    }
    float inv = 1.f / sum;
    __syncthreads();
    float (*os)[64][33] = ks;
#pragma unroll
    for (int j = 0; j < 32; ++j) os[h][l][j] = o[j] * inv;
    __syncthreads();

    int t = threadIdx.x;
    if (t < 128) {
        int h2 = t >> 5, j = t & 31;
        float s = 0.f;
#pragma unroll
        for (int m = 0; m < 64; ++m) s += os[h2][m][j];
        ob[t] = s * (1.f / 64.f);
    }
    __syncthreads();
    if (t < 128) {
        float val = outb[t];
        const float* wrow = outw + (size_t)t * 128;
#pragma unroll 8
        for (int k4 = 0; k4 < 32; ++k4) {
            float4 wv = *(const float4*)(wrow + k4 * 4);
            val += wv.x * ob[k4 * 4] + wv.y * ob[k4 * 4 + 1]
                 + wv.z * ob[k4 * 4 + 2] + wv.w * ob[k4 * 4 + 3];
        }
        out[(size_t)b * 128 + t] = val;
    }
}

// ---------------- tar_embed gather ----------------

__global__ void tar_kernel(const float* __restrict__ enc, const int* __restrict__ data_poi,
                           float* __restrict__ out)
{
    int i = blockIdx.x * blockDim.x + threadIdx.x;
    if (i >= BATCH * 128) return;
    int r = i >> 7, c = i & 127;
    out[i] = enc[(size_t)data_poi[r] * 128 + c];
}

// ---------------- launch ----------------

extern "C" void kernel_launch(void* const* d_in, const int* in_sizes, int n_in,
                              void* d_out, int out_size, void* d_ws, size_t ws_size,
                              hipStream_t stream)
{
    const float* poi      = (const float*)d_in[0];
    const int*   edges    = (const int*)d_in[1];
    const float* dvec     = (const float*)d_in[2];
    const int*   data_poi = (const int*)d_in[3];
    const int*   data_x   = (const int*)d_in[4];
    const float* lin_w    = (const float*)d_in[5];
    const float* lin_b    = (const float*)d_in[6];
    const float* inw      = (const float*)d_in[7];
    const float* inb      = (const float*)d_in[8];
    const float* outw     = (const float*)d_in[9];
    const float* outb     = (const float*)d_in[10];
    const int* e0 = edges;
    const int* e1 = edges + NEDGE;

    char* ws = (char*)d_ws;
    size_t off = 0;
    auto alloc = [&](size_t bytes) -> void* {
        void* p = ws + off;
        off = (off + bytes + 255) & ~(size_t)255;
        return p;
    };
    int*      counts = (int*)     alloc(NPOI * 4);
    int*      offs   = (int*)     alloc((NPOI + 1) * 4);
    int*      bsum   = (int*)     alloc(SCAN_BLOCKS * 4);
    int*      bcur   = (int*)     alloc(NB * 4);
    unsigned* ew     = (unsigned*)alloc((size_t)EAUG * 4);
    float*    enc    = (float*)   alloc((size_t)NPOI * 128 * 4);
    _Float16* enc_h  = (_Float16*)alloc((size_t)NPOI * 128 * 2);
    _Float16* linw_h = (_Float16*)alloc((size_t)2 * 128 * 128 * 2);
    _Float16* inw_h  = (_Float16*)alloc((size_t)384 * 128 * 2);
    float*    qkvb   = (float*)   alloc((size_t)BATCH * SEQL * 384 * 4);   // 50.3 MB
    // aliases inside qkvb's region (lifetimes disjoint from qkvb itself):
    //   poi_h   [0, 12.8 MB)   — written by cvt, read by GEMM1
    //   staging [16, 29.2 MB)  — written by partition, read by csr_sort (dead before GEMM1's hbuf? no:
    //                            staging dead after csr_sort which precedes GEMM1)
    //   hbuf    [30, 42.8 MB)  — GEMM1/2 output, aggregate input
    _Float16*           poi_h   = (_Float16*)qkvb;
    unsigned long long* staging = (unsigned long long*)((char*)qkvb + 16ull * 1024 * 1024);
    _Float16*           hbuf    = (_Float16*)((char*)qkvb + 30ull * 1024 * 1024);

    hipMemsetAsync(counts, 0, NPOI * 4, stream);

    cvt_all_kernel<<<(N4_POI + N4_LIN + N4_INW + 255) / 256, 256, 0, stream>>>(
        poi, lin_w, inw, poi_h, linw_h, inw_h);

    count_edges_kernel<<<(NEDGE + 255) / 256, 256, 0, stream>>>(e0, e1, counts);
    block_sum_kernel<<<SCAN_BLOCKS, 256, 0, stream>>>(counts, bsum);
    scan_chunk_kernel<<<SCAN_BLOCKS, 256, 0, stream>>>(counts, bsum, offs, bcur);
    partition_kernel<<<P1_BLOCKS, 256, 0, stream>>>(e0, e1, dvec, counts, bcur, staging);
    csr_sort_kernel<<<NB, 256, 0, stream>>>(staging, offs, ew);

    // 2 graph-conv layers
    gemm_mfma_f16<_Float16><<<dim3(2, (NPOI + 63) / 64), 256, 0, stream>>>(
        poi_h, nullptr, linw_h, lin_b, hbuf, NPOI, 128);
    aggregate_kernel<<<NPOI, 64, 0, stream>>>(hbuf, offs, ew, enc, enc_h);
    gemm_mfma_f16<_Float16><<<dim3(2, (NPOI + 63) / 64), 256, 0, stream>>>(
        enc_h, nullptr, linw_h + 128 * 128, lin_b + 128, hbuf, NPOI, 128);
    aggregate_kernel<<<NPOI, 64, 0, stream>>>(hbuf, offs, ew, enc, enc_h);

    // attention (qkv gemm -> fused attn+mean+out_proj -> d_out)
    gemm_mfma_f16<float><<<dim3(6, BATCH * SEQL / 64), 256, 0, stream>>>(
        enc_h, data_x, inw_h, inb, qkvb, BATCH * SEQL, 384);
    attn_fused_kernel<<<BATCH, 256, 0, stream>>>(qkvb, outw, outb, (float*)d_out);

    tar_kernel<<<(BATCH * 128 + 255) / 256, 256, 0, stream>>>(
        enc, data_poi, (float*)d_out + BATCH * 128);
}

// Round 7
// 345.568 us; speedup vs baseline: 2.7596x; 1.1853x over previous
//
#include <hip/hip_runtime.h>
#include <hip/hip_fp16.h>
#include <type_traits>

#define NPOI 50000
#define EMB 128
#define NEDGE 800000
#define EAUG (2 * NEDGE + NPOI)
#define BATCH 512
#define SEQL 64
#define NHEADS 4
#define HDIM 32
#define SCAN_BLOCKS ((NPOI + 255) / 256)   // 196
#define NB SCAN_BLOCKS                      // 256-node buckets
#define P1_BLOCKS ((NEDGE + 2047) / 2048)   // 391
#define SLAB_CAP 10240                      // per-bucket slab (mean 8192, ~22 sigma margin)
#define BUCKET_CAP 10240                    // sorted bucket incl self-loops (mean 8448)

typedef _Float16 half8 __attribute__((ext_vector_type(8)));
typedef _Float16 half4 __attribute__((ext_vector_type(4)));
typedef _Float16 half2t __attribute__((ext_vector_type(2)));
typedef float f32x4 __attribute__((ext_vector_type(4)));
typedef unsigned long long u64;

union HBits { _Float16 h; unsigned short u; };

// ---------------- fused fp32 -> fp16 convert (poi, lin_w, in_proj_w) ----------------

#define N4_POI (NPOI * 128 / 4)
#define N4_LIN (2 * 128 * 128 / 4)
#define N4_INW (384 * 128 / 4)

__global__ void cvt_all_kernel(const float* __restrict__ poi, const float* __restrict__ linw,
                               const float* __restrict__ inw,
                               _Float16* __restrict__ poi_h, _Float16* __restrict__ linw_h,
                               _Float16* __restrict__ inw_h) {
    int i = blockIdx.x * blockDim.x + threadIdx.x;
    const float* src; _Float16* dst; int j = i;
    if (i < N4_POI) { src = poi; dst = poi_h; }
    else if (i < N4_POI + N4_LIN) { j = i - N4_POI; src = linw; dst = linw_h; }
    else if (i < N4_POI + N4_LIN + N4_INW) { j = i - N4_POI - N4_LIN; src = inw; dst = inw_h; }
    else return;
    float4 v = ((const float4*)src)[j];
    half4 h = { (_Float16)v.x, (_Float16)v.y, (_Float16)v.z, (_Float16)v.w };
    ((half4*)dst)[j] = h;
}

__global__ void init_bcur_kernel(int* __restrict__ bcur) {
    int t = blockIdx.x * blockDim.x + threadIdx.x;
    if (t < NB) bcur[t] = t * SLAB_CAP;
}

// ---------------- phase 1: LDS-buffered multisplit into static per-bucket slabs ----------------
// entry u64 = s(16)<<48 | d(16)<<32 | fp32(dist). No degree dependency; self-loops synthesized later.

__global__ __launch_bounds__(256) void partition_kernel(
    const int* __restrict__ e0, const int* __restrict__ e1,
    const float* __restrict__ dv, int* __restrict__ bcur,
    u64* __restrict__ staging)
{
    __shared__ u64 stg[4096];
    __shared__ int lh[NB], lbase[NB], gb[NB];
    __shared__ int sc[256];
    const int t = threadIdx.x;
    const int blockBase = blockIdx.x * 2048;
    for (int j = t; j < NB; j += 256) lh[j] = 0;
    __syncthreads();

    u64 vals[16];
    unsigned br[16];
#pragma unroll
    for (int i = 0; i < 8; ++i) {
        br[2 * i] = 0xFFFFFFFFu;
        br[2 * i + 1] = 0xFFFFFFFFu;
        int g = blockBase + i * 256 + t;
        if (g < NEDGE) {
            int s = e0[g], d = e1[g];
            unsigned db = __float_as_uint(dv[g]);
            vals[2 * i]     = ((u64)s << 48) | ((u64)d << 32) | db;
            vals[2 * i + 1] = ((u64)d << 48) | ((u64)s << 32) | db;
            int bs = s >> 8, bd = d >> 8;
            int rs = atomicAdd(&lh[bs], 1);
            int rd_ = atomicAdd(&lh[bd], 1);
            br[2 * i]     = ((unsigned)bs << 16) | (unsigned)rs;
            br[2 * i + 1] = ((unsigned)bd << 16) | (unsigned)rd_;
        }
    }
    __syncthreads();
    sc[t] = (t < NB) ? lh[t] : 0;
    __syncthreads();
    for (int o = 1; o < 256; o <<= 1) {
        int u = (t >= o) ? sc[t - o] : 0;
        __syncthreads();
        sc[t] += u;
        __syncthreads();
    }
    if (t < NB) {
        lbase[t] = sc[t] - lh[t];
        gb[t] = (lh[t] > 0) ? atomicAdd(&bcur[t], lh[t]) : 0;
    }
    __syncthreads();
#pragma unroll
    for (int i = 0; i < 16; ++i) {
        if (br[i] != 0xFFFFFFFFu) {
            int b = br[i] >> 16, r = br[i] & 0xFFFF;
            stg[lbase[b] + r] = vals[i];
        }
    }
    __syncthreads();
    const int total = sc[255];
    for (int j = t; j < total; j += 256) {
        u64 v = stg[j];
        int b = (int)(v >> 56);   // s >> 8
        staging[(size_t)gb[b] + (unsigned)(j - lbase[b])] = v;
    }
}

// ---------------- per-bucket histogram -> counts (coalesced, no global atomics) ----------------

__global__ __launch_bounds__(256) void hist_kernel(const u64* __restrict__ staging,
                                                   const int* __restrict__ bcur,
                                                   int* __restrict__ counts,
                                                   int* __restrict__ bsum) {
    __shared__ int cnt[256];
    __shared__ int red[256];
    const int b = blockIdx.x, t = threadIdx.x;
    cnt[t] = 0;
    __syncthreads();
    const int base = b * SLAB_CAP;
    const int n = bcur[b] - base;
    for (int j = t; j < n; j += 256)
        atomicAdd(&cnt[(int)(staging[base + j] >> 48) & 255], 1);
    __syncthreads();
    int node = b * 256 + t;
    int rowsz = 0;
    if (node < NPOI) {
        counts[node] = cnt[t];
        rowsz = cnt[t] + 1;   // + self loop
    }
    red[t] = rowsz;
    __syncthreads();
    for (int o = 128; o > 0; o >>= 1) {
        if (t < o) red[t] += red[t + o];
        __syncthreads();
    }
    if (t == 0) bsum[b] = red[0];
}

// fused mid-scan + chunk-scan; also emits rd = rsqrt(deg)
__global__ __launch_bounds__(256) void scan_chunk_kernel(const int* __restrict__ counts,
                                                         const int* __restrict__ bsum,
                                                         int* __restrict__ offs,
                                                         float* __restrict__ rd) {
    __shared__ int shb[256];
    __shared__ int sh[256];
    __shared__ int base_sh;
    int b = blockIdx.x, t = threadIdx.x;
    shb[t] = (t < SCAN_BLOCKS) ? bsum[t] : 0;
    __syncthreads();
    int partial = 0;
    for (int j = t; j < b; j += 256) partial += shb[j];
    sh[t] = partial;
    __syncthreads();
    for (int o = 128; o > 0; o >>= 1) {
        if (t < o) sh[t] += sh[t + o];
        __syncthreads();
    }
    if (t == 0) base_sh = sh[0];
    __syncthreads();
    int bbase = base_sh;
    __syncthreads();
    int i = b * 256 + t;
    int v = (i < NPOI) ? (counts[i] + 1) : 0;
    sh[t] = v;
    __syncthreads();
    for (int o = 1; o < 256; o <<= 1) {
        int u = (t >= o) ? sh[t - o] : 0;
        __syncthreads();
        sh[t] += u;
        __syncthreads();
    }
    int excl = sh[t] - v + bbase;
    if (i < NPOI) {
        offs[i] = excl;
        rd[i] = rsqrtf((float)v);
        if (i == NPOI - 1) offs[NPOI] = excl + v;
    }
}

// ---------------- phase 2: per-bucket counting sort + weight compute -> packed CSR ----------------

__global__ __launch_bounds__(256) void csr_sort_kernel(
    const u64* __restrict__ staging, const int* __restrict__ bcur,
    const int* __restrict__ offs, const float* __restrict__ rd,
    unsigned* __restrict__ ew)
{
    const int k = blockIdx.x;
    const int node0 = k * 256;
    const int node1 = (node0 + 256 < NPOI) ? node0 + 256 : NPOI;
    __shared__ unsigned outb[BUCKET_CAP];
    __shared__ int cnt[256], base2[256];
    __shared__ float rdl[256];
    const int t = threadIdx.x;
    const int node = node0 + t;
    cnt[t] = 0;
    rdl[t] = (node < NPOI) ? rd[node] : 0.f;
    __syncthreads();
    const int sb = k * SLAB_CAP;
    const int n = bcur[k] - sb;
    for (int j = t; j < n; j += 256)
        atomicAdd(&cnt[(int)(staging[sb + j] >> 48) & 255], 1);
    __syncthreads();
    int rowsz = (node < NPOI) ? cnt[t] + 1 : 0;
    base2[t] = rowsz;
    __syncthreads();
    for (int o = 1; o < 256; o <<= 1) {
        int u = (t >= o) ? base2[t - o] : 0;
        __syncthreads();
        base2[t] += u;
        __syncthreads();
    }
    int myexc = base2[t] - rowsz;
    __syncthreads();
    base2[t] = myexc;
    cnt[t] = 0;
    __syncthreads();
    for (int j = t; j < n; j += 256) {
        u64 e = staging[sb + j];
        int sl = (int)(e >> 48) & 255;
        int d = (int)(e >> 32) & 0xFFFF;
        float dist = __uint_as_float((unsigned)e);
        float w = rdl[sl] * rd[d] * expf(-dist * dist);
        HBits cv; cv.h = (_Float16)w;
        int r = atomicAdd(&cnt[sl], 1);
        outb[base2[sl] + r] = ((unsigned)d << 16) | cv.u;
    }
    __syncthreads();
    if (node < NPOI) {   // self loop in last slot of the row
        float w = rdl[t] * rdl[t];
        HBits cv; cv.h = (_Float16)w;
        outb[base2[t] + cnt[t]] = ((unsigned)node << 16) | cv.u;
    }
    __syncthreads();
    const int beg = offs[node0];
    const int ntot = offs[node1] - beg;
    for (int j = t; j < ntot; j += 256) ew[beg + j] = outb[j];   // coalesced
}

// ---------------- fp16 MFMA GEMM: C[M,N] = A(gathered)[M,128] @ B[N,128]^T + bias ----------------

template <typename OutT>
__global__ __launch_bounds__(256) void gemm_mfma_f16(
    const _Float16* __restrict__ A, const int* __restrict__ gidx,
    const _Float16* __restrict__ B, const float* __restrict__ bias,
    OutT* __restrict__ C, int M, int N)
{
    __shared__ _Float16 Asl[64][136];
    __shared__ _Float16 Bsl[64][136];
    const int tid = threadIdx.x;
    const int n0 = blockIdx.x * 64;
    const int m0 = blockIdx.y * 64;

#pragma unroll
    for (int i = 0; i < 4; ++i) {
        int u = i * 256 + tid;
        int r = u >> 4;
        int c = u & 15;
        int row = m0 + r;
        int ar = (row < M) ? (gidx ? gidx[row] : row) : 0;
        *(float4*)&Asl[r][c * 8] = *(const float4*)(A + (size_t)ar * 128 + c * 8);
        *(float4*)&Bsl[r][c * 8] = *(const float4*)(B + (size_t)(n0 + r) * 128 + c * 8);
    }
    __syncthreads();

    const int wave = tid >> 6;
    const int lane = tid & 63;
    const int l15 = lane & 15;
    const int quad = lane >> 4;

    f32x4 acc[4];
#pragma unroll
    for (int mt = 0; mt < 4; ++mt) acc[mt] = (f32x4){0.f, 0.f, 0.f, 0.f};

#pragma unroll
    for (int ks = 0; ks < 4; ++ks) {
        half8 bfrag = *(const half8*)&Bsl[wave * 16 + l15][quad * 8 + ks * 32];
#pragma unroll
        for (int mt = 0; mt < 4; ++mt) {
            half8 afrag = *(const half8*)&Asl[mt * 16 + l15][quad * 8 + ks * 32];
            acc[mt] = __builtin_amdgcn_mfma_f32_16x16x32_f16(afrag, bfrag, acc[mt], 0, 0, 0);
        }
    }

    int col = n0 + wave * 16 + l15;
    float bv = bias[col];
#pragma unroll
    for (int mt = 0; mt < 4; ++mt) {
#pragma unroll
        for (int r = 0; r < 4; ++r) {
            int m = m0 + mt * 16 + quad * 4 + r;
            if (m < M) {
                float v = acc[mt][r] + bv;
                if constexpr (std::is_same<OutT, _Float16>::value)
                    C[(size_t)m * N + col] = (_Float16)v;
                else
                    C[(size_t)m * N + col] = v;
            }
        }
    }
}

// ---------------- CSR aggregate + leaky-relu + L2 normalize ----------------

__global__ __launch_bounds__(64) void aggregate_kernel(
    const _Float16* __restrict__ h, const int* __restrict__ offs,
    const unsigned* __restrict__ ew, float* __restrict__ enc_out,
    _Float16* __restrict__ enc_h)
{
    const int row = blockIdx.x;
    const int lane = threadIdx.x;  // cols 2*lane, 2*lane+1
    const int beg = offs[row];
    const int end = offs[row + 1];
    float ax = 0.f, ay = 0.f;
#pragma unroll 4
    for (int e = beg; e < end; ++e) {
        unsigned p = ew[e];
        HBits cv; cv.u = (unsigned short)(p & 0xffffu);
        float w = (float)cv.h;
        int d = p >> 16;
        half2t hv = *(const half2t*)(h + (size_t)d * 128 + lane * 2);
        ax += w * (float)hv[0];
        ay += w * (float)hv[1];
    }
    ax = ax >= 0.f ? ax : 0.01f * ax;
    ay = ay >= 0.f ? ay : 0.01f * ay;
    float ss = ax * ax + ay * ay;
#pragma unroll
    for (int o = 32; o > 0; o >>= 1) ss += __shfl_xor(ss, o);
    float inv = 1.f / fmaxf(sqrtf(ss), 1e-12f);
    float ex = ax * inv, ey = ay * inv;
    *(float2*)(enc_out + (size_t)row * 128 + lane * 2) = make_float2(ex, ey);
    half2t hv = { (_Float16)ex, (_Float16)ey };
    *(half2t*)(enc_h + (size_t)row * 128 + lane * 2) = hv;
}

// ---------------- fused attention + mean + out_proj ----------------

__global__ __launch_bounds__(256) void attn_fused_kernel(
    const float* __restrict__ qkv, const float* __restrict__ outw,
    const float* __restrict__ outb, float* __restrict__ out)
{
    const int b = blockIdx.x;
    const int h = threadIdx.x >> 6;
    const int l = threadIdx.x & 63;
    __shared__ float ks[NHEADS][64][33];
    __shared__ float vs[NHEADS][64][33];
    __shared__ float ob[128];
    const float* base = qkv + (size_t)b * SEQL * 384;
    const float scale = 0.17677669529663687f;
    float q[32];
#pragma unroll
    for (int j0 = 0; j0 < 32; j0 += 4) {
        float4 qv = *(const float4*)(base + (size_t)l * 384 + h * 32 + j0);
        q[j0 + 0] = qv.x * scale; q[j0 + 1] = qv.y * scale;
        q[j0 + 2] = qv.z * scale; q[j0 + 3] = qv.w * scale;
        float4 kv = *(const float4*)(base + (size_t)l * 384 + 128 + h * 32 + j0);
        ks[h][l][j0 + 0] = kv.x; ks[h][l][j0 + 1] = kv.y;
        ks[h][l][j0 + 2] = kv.z; ks[h][l][j0 + 3] = kv.w;
        float4 vv = *(const float4*)(base + (size_t)l * 384 + 256 + h * 32 + j0);
        vs[h][l][j0 + 0] = vv.x; vs[h][l][j0 + 1] = vv.y;
        vs[h][l][j0 + 2] = vv.z; vs[h][l][j0 + 3] = vv.w;
    }
    __syncthreads();

    float mx = -1e30f, sum = 0.f;
    float o[32];
#pragma unroll
    for (int j = 0; j < 32; ++j) o[j] = 0.f;
#pragma unroll 2
    for (int m = 0; m < 64; ++m) {
        float s = 0.f;
#pragma unroll
        for (int j = 0; j < 32; ++j) s += q[j] * ks[h][m][j];
        float nm = fmaxf(mx, s);
        float alpha = __expf(mx - nm);
        float p = __expf(s - nm);
        sum = sum * alpha + p;
        mx = nm;
#pragma unroll
        for (int j = 0; j < 32; ++j) o[j] = o[j] * alpha + p * vs[h][m][j];
    }
    float inv = 1.f / sum;
    __syncthreads();
    float (*os)[64][33] = ks;
#pragma unroll
    for (int j = 0; j < 32; ++j) os[h][l][j] = o[j] * inv;
    __syncthreads();

    int t = threadIdx.x;
    if (t < 128) {
        int h2 = t >> 5, j = t & 31;
        float s = 0.f;
#pragma unroll
        for (int m = 0; m < 64; ++m) s += os[h2][m][j];
        ob[t] = s * (1.f / 64.f);
    }
    __syncthreads();
    if (t < 128) {
        float val = outb[t];
        const float* wrow = outw + (size_t)t * 128;
#pragma unroll 8
        for (int k4 = 0; k4 < 32; ++k4) {
            float4 wv = *(const float4*)(wrow + k4 * 4);
            val += wv.x * ob[k4 * 4] + wv.y * ob[k4 * 4 + 1]
                 + wv.z * ob[k4 * 4 + 2] + wv.w * ob[k4 * 4 + 3];
        }
        out[(size_t)b * 128 + t] = val;
    }
}

// ---------------- tar_embed gather ----------------

__global__ void tar_kernel(const float* __restrict__ enc, const int* __restrict__ data_poi,
                           float* __restrict__ out)
{
    int i = blockIdx.x * blockDim.x + threadIdx.x;
    if (i >= BATCH * 128) return;
    int r = i >> 7, c = i & 127;
    out[i] = enc[(size_t)data_poi[r] * 128 + c];
}

// ---------------- launch ----------------

extern "C" void kernel_launch(void* const* d_in, const int* in_sizes, int n_in,
                              void* d_out, int out_size, void* d_ws, size_t ws_size,
                              hipStream_t stream)
{
    const float* poi      = (const float*)d_in[0];
    const int*   edges    = (const int*)d_in[1];
    const float* dvec     = (const float*)d_in[2];
    const int*   data_poi = (const int*)d_in[3];
    const int*   data_x   = (const int*)d_in[4];
    const float* lin_w    = (const float*)d_in[5];
    const float* lin_b    = (const float*)d_in[6];
    const float* inw      = (const float*)d_in[7];
    const float* inb      = (const float*)d_in[8];
    const float* outw     = (const float*)d_in[9];
    const float* outb     = (const float*)d_in[10];
    const int* e0 = edges;
    const int* e1 = edges + NEDGE;

    char* ws = (char*)d_ws;
    size_t off = 0;
    auto alloc = [&](size_t bytes) -> void* {
        void* p = ws + off;
        off = (off + bytes + 255) & ~(size_t)255;
        return p;
    };
    int*      counts = (int*)     alloc(NPOI * 4);
    int*      offs   = (int*)     alloc((NPOI + 1) * 4);
    int*      bsum   = (int*)     alloc(SCAN_BLOCKS * 4);
    int*      bcur   = (int*)     alloc(NB * 4);
    float*    rd     = (float*)   alloc(NPOI * 4);
    unsigned* ew     = (unsigned*)alloc((size_t)EAUG * 4);
    float*    enc    = (float*)   alloc((size_t)NPOI * 128 * 4);
    _Float16* enc_h  = (_Float16*)alloc((size_t)NPOI * 128 * 2);
    _Float16* linw_h = (_Float16*)alloc((size_t)2 * 128 * 128 * 2);
    _Float16* inw_h  = (_Float16*)alloc((size_t)384 * 128 * 2);
    float*    qkvb   = (float*)   alloc((size_t)BATCH * SEQL * 384 * 4);   // 50.3 MB
    // aliases inside qkvb's region (all dead before the qkv GEMM writes qkvb):
    //   poi_h   [ 0, 12.8 MB)  — cvt -> GEMM1
    //   staging [16, 32.1 MB)  — partition -> hist/csr_sort (196*10240*8 B)
    //   hbuf    [33, 45.8 MB)  — GEMM1/2 -> aggregate
    _Float16* poi_h   = (_Float16*)qkvb;
    u64*      staging = (u64*)((char*)qkvb + 16ull * 1024 * 1024);
    _Float16* hbuf    = (_Float16*)((char*)qkvb + 33ull * 1024 * 1024);

    cvt_all_kernel<<<(N4_POI + N4_LIN + N4_INW + 255) / 256, 256, 0, stream>>>(
        poi, lin_w, inw, poi_h, linw_h, inw_h);

    init_bcur_kernel<<<1, 256, 0, stream>>>(bcur);
    partition_kernel<<<P1_BLOCKS, 256, 0, stream>>>(e0, e1, dvec, bcur, staging);
    hist_kernel<<<NB, 256, 0, stream>>>(staging, bcur, counts, bsum);
    scan_chunk_kernel<<<SCAN_BLOCKS, 256, 0, stream>>>(counts, bsum, offs, rd);
    csr_sort_kernel<<<NB, 256, 0, stream>>>(staging, bcur, offs, rd, ew);

    // 2 graph-conv layers
    gemm_mfma_f16<_Float16><<<dim3(2, (NPOI + 63) / 64), 256, 0, stream>>>(
        poi_h, nullptr, linw_h, lin_b, hbuf, NPOI, 128);
    aggregate_kernel<<<NPOI, 64, 0, stream>>>(hbuf, offs, ew, enc, enc_h);
    gemm_mfma_f16<_Float16><<<dim3(2, (NPOI + 63) / 64), 256, 0, stream>>>(
        enc_h, nullptr, linw_h + 128 * 128, lin_b + 128, hbuf, NPOI, 128);
    aggregate_kernel<<<NPOI, 64, 0, stream>>>(hbuf, offs, ew, enc, enc_h);

    // attention (qkv gemm -> fused attn+mean+out_proj -> d_out)
    gemm_mfma_f16<float><<<dim3(6, BATCH * SEQL / 64), 256, 0, stream>>>(
        enc_h, data_x, inw_h, inb, qkvb, BATCH * SEQL, 384);
    attn_fused_kernel<<<BATCH, 256, 0, stream>>>(qkvb, outw, outb, (float*)d_out);

    tar_kernel<<<(BATCH * 128 + 255) / 256, 256, 0, stream>>>(
        enc, data_poi, (float*)d_out + BATCH * 128);
}

// Round 8
// 307.182 us; speedup vs baseline: 3.1045x; 1.1250x over previous
//
#include <hip/hip_runtime.h>
#include <hip/hip_fp16.h>
#include <type_traits>

#define NPOI 50000
#define EMB 128
#define NEDGE 800000
#define EAUG (2 * NEDGE + NPOI)
#define BATCH 512
#define SEQL 64
#define NHEADS 4
#define HDIM 32
#define SCAN_BLOCKS ((NPOI + 255) / 256)   // 196
#define NB SCAN_BLOCKS                      // 256-node buckets
#define P1_BLOCKS ((NEDGE + 2047) / 2048)   // 391
#define SLAB_CAP 10240                      // per-bucket slab (mean 8192, ~22 sigma margin)
#define BUCKET_CAP 10240                    // sorted bucket incl self-loops (mean 8448)

typedef _Float16 half8 __attribute__((ext_vector_type(8)));
typedef _Float16 half4 __attribute__((ext_vector_type(4)));
typedef _Float16 half2t __attribute__((ext_vector_type(2)));
typedef float f32x4 __attribute__((ext_vector_type(4)));
typedef unsigned long long u64;

union HBits { _Float16 h; unsigned short u; };

// ---------------- fused fp32 -> fp16 convert (poi, lin_w, in_proj_w) ----------------

#define N4_POI (NPOI * 128 / 4)
#define N4_LIN (2 * 128 * 128 / 4)
#define N4_INW (384 * 128 / 4)

__global__ void cvt_all_kernel(const float* __restrict__ poi, const float* __restrict__ linw,
                               const float* __restrict__ inw,
                               _Float16* __restrict__ poi_h, _Float16* __restrict__ linw_h,
                               _Float16* __restrict__ inw_h) {
    int i = blockIdx.x * blockDim.x + threadIdx.x;
    const float* src; _Float16* dst; int j = i;
    if (i < N4_POI) { src = poi; dst = poi_h; }
    else if (i < N4_POI + N4_LIN) { j = i - N4_POI; src = linw; dst = linw_h; }
    else if (i < N4_POI + N4_LIN + N4_INW) { j = i - N4_POI - N4_LIN; src = inw; dst = inw_h; }
    else return;
    float4 v = ((const float4*)src)[j];
    half4 h = { (_Float16)v.x, (_Float16)v.y, (_Float16)v.z, (_Float16)v.w };
    ((half4*)dst)[j] = h;
}

__global__ void init_bcur_kernel(int* __restrict__ bcur) {
    int t = blockIdx.x * blockDim.x + threadIdx.x;
    if (t < NB) bcur[t] = t * SLAB_CAP;
}

// ---------------- phase 1: LDS-buffered multisplit into static per-bucket slabs ----------------

__global__ __launch_bounds__(256) void partition_kernel(
    const int* __restrict__ e0, const int* __restrict__ e1,
    const float* __restrict__ dv, int* __restrict__ bcur,
    u64* __restrict__ staging)
{
    __shared__ u64 stg[4096];
    __shared__ int lh[NB], lbase[NB], gb[NB];
    __shared__ int sc[256];
    const int t = threadIdx.x;
    const int blockBase = blockIdx.x * 2048;
    for (int j = t; j < NB; j += 256) lh[j] = 0;
    __syncthreads();

    u64 vals[16];
    unsigned br[16];
#pragma unroll
    for (int i = 0; i < 8; ++i) {
        br[2 * i] = 0xFFFFFFFFu;
        br[2 * i + 1] = 0xFFFFFFFFu;
        int g = blockBase + i * 256 + t;
        if (g < NEDGE) {
            int s = e0[g], d = e1[g];
            unsigned db = __float_as_uint(dv[g]);
            vals[2 * i]     = ((u64)s << 48) | ((u64)d << 32) | db;
            vals[2 * i + 1] = ((u64)d << 48) | ((u64)s << 32) | db;
            int bs = s >> 8, bd = d >> 8;
            int rs = atomicAdd(&lh[bs], 1);
            int rd_ = atomicAdd(&lh[bd], 1);
            br[2 * i]     = ((unsigned)bs << 16) | (unsigned)rs;
            br[2 * i + 1] = ((unsigned)bd << 16) | (unsigned)rd_;
        }
    }
    __syncthreads();
    sc[t] = (t < NB) ? lh[t] : 0;
    __syncthreads();
    for (int o = 1; o < 256; o <<= 1) {
        int u = (t >= o) ? sc[t - o] : 0;
        __syncthreads();
        sc[t] += u;
        __syncthreads();
    }
    if (t < NB) {
        lbase[t] = sc[t] - lh[t];
        gb[t] = (lh[t] > 0) ? atomicAdd(&bcur[t], lh[t]) : 0;
    }
    __syncthreads();
#pragma unroll
    for (int i = 0; i < 16; ++i) {
        if (br[i] != 0xFFFFFFFFu) {
            int b = br[i] >> 16, r = br[i] & 0xFFFF;
            stg[lbase[b] + r] = vals[i];
        }
    }
    __syncthreads();
    const int total = sc[255];
    for (int j = t; j < total; j += 256) {
        u64 v = stg[j];
        int b = (int)(v >> 56);
        staging[(size_t)gb[b] + (unsigned)(j - lbase[b])] = v;
    }
}

// ---------------- per-bucket histogram -> counts (coalesced, no global atomics) ----------------

__global__ __launch_bounds__(256) void hist_kernel(const u64* __restrict__ staging,
                                                   const int* __restrict__ bcur,
                                                   int* __restrict__ counts,
                                                   int* __restrict__ bsum) {
    __shared__ int cnt[256];
    __shared__ int red[256];
    const int b = blockIdx.x, t = threadIdx.x;
    cnt[t] = 0;
    __syncthreads();
    const int base = b * SLAB_CAP;
    const int n = bcur[b] - base;
    for (int j = t; j < n; j += 256)
        atomicAdd(&cnt[(int)(staging[base + j] >> 48) & 255], 1);
    __syncthreads();
    int node = b * 256 + t;
    int rowsz = 0;
    if (node < NPOI) {
        counts[node] = cnt[t];
        rowsz = cnt[t] + 1;
    }
    red[t] = rowsz;
    __syncthreads();
    for (int o = 128; o > 0; o >>= 1) {
        if (t < o) red[t] += red[t + o];
        __syncthreads();
    }
    if (t == 0) bsum[b] = red[0];
}

// fused mid-scan + chunk-scan; also emits rd = rsqrt(deg)
__global__ __launch_bounds__(256) void scan_chunk_kernel(const int* __restrict__ counts,
                                                         const int* __restrict__ bsum,
                                                         int* __restrict__ offs,
                                                         float* __restrict__ rd) {
    __shared__ int shb[256];
    __shared__ int sh[256];
    __shared__ int base_sh;
    int b = blockIdx.x, t = threadIdx.x;
    shb[t] = (t < SCAN_BLOCKS) ? bsum[t] : 0;
    __syncthreads();
    int partial = 0;
    for (int j = t; j < b; j += 256) partial += shb[j];
    sh[t] = partial;
    __syncthreads();
    for (int o = 128; o > 0; o >>= 1) {
        if (t < o) sh[t] += sh[t + o];
        __syncthreads();
    }
    if (t == 0) base_sh = sh[0];
    __syncthreads();
    int bbase = base_sh;
    __syncthreads();
    int i = b * 256 + t;
    int v = (i < NPOI) ? (counts[i] + 1) : 0;
    sh[t] = v;
    __syncthreads();
    for (int o = 1; o < 256; o <<= 1) {
        int u = (t >= o) ? sh[t - o] : 0;
        __syncthreads();
        sh[t] += u;
        __syncthreads();
    }
    int excl = sh[t] - v + bbase;
    if (i < NPOI) {
        offs[i] = excl;
        rd[i] = rsqrtf((float)v);
        if (i == NPOI - 1) offs[NPOI] = excl + v;
    }
}

// ---------------- phase 2: per-bucket counting sort + weight compute -> packed CSR ----------------

__global__ __launch_bounds__(256) void csr_sort_kernel(
    const u64* __restrict__ staging, const int* __restrict__ bcur,
    const int* __restrict__ offs, const float* __restrict__ rd,
    unsigned* __restrict__ ew)
{
    const int k = blockIdx.x;
    const int node0 = k * 256;
    const int node1 = (node0 + 256 < NPOI) ? node0 + 256 : NPOI;
    __shared__ unsigned outb[BUCKET_CAP];
    __shared__ int cnt[256], base2[256];
    __shared__ float rdl[256];
    const int t = threadIdx.x;
    const int node = node0 + t;
    cnt[t] = 0;
    rdl[t] = (node < NPOI) ? rd[node] : 0.f;
    __syncthreads();
    const int sb = k * SLAB_CAP;
    const int n = bcur[k] - sb;
    for (int j = t; j < n; j += 256)
        atomicAdd(&cnt[(int)(staging[sb + j] >> 48) & 255], 1);
    __syncthreads();
    int rowsz = (node < NPOI) ? cnt[t] + 1 : 0;
    base2[t] = rowsz;
    __syncthreads();
    for (int o = 1; o < 256; o <<= 1) {
        int u = (t >= o) ? base2[t - o] : 0;
        __syncthreads();
        base2[t] += u;
        __syncthreads();
    }
    int myexc = base2[t] - rowsz;
    __syncthreads();
    base2[t] = myexc;
    cnt[t] = 0;
    __syncthreads();
    for (int j = t; j < n; j += 256) {
        u64 e = staging[sb + j];
        int sl = (int)(e >> 48) & 255;
        int d = (int)(e >> 32) & 0xFFFF;
        float dist = __uint_as_float((unsigned)e);
        float w = rdl[sl] * rd[d] * expf(-dist * dist);
        HBits cv; cv.h = (_Float16)w;
        int r = atomicAdd(&cnt[sl], 1);
        outb[base2[sl] + r] = ((unsigned)d << 16) | cv.u;
    }
    __syncthreads();
    if (node < NPOI) {
        float w = rdl[t] * rdl[t];
        HBits cv; cv.h = (_Float16)w;
        outb[base2[t] + cnt[t]] = ((unsigned)node << 16) | cv.u;
    }
    __syncthreads();
    const int beg = offs[node0];
    const int ntot = offs[node1] - beg;
    for (int j = t; j < ntot; j += 256) ew[beg + j] = outb[j];
}

// ---------------- fp16 MFMA GEMM: C[M,N] = A(gathered)[M,128] @ B[N,128]^T + bias ----------------

template <typename OutT>
__global__ __launch_bounds__(256) void gemm_mfma_f16(
    const _Float16* __restrict__ A, const int* __restrict__ gidx,
    const _Float16* __restrict__ B, const float* __restrict__ bias,
    OutT* __restrict__ C, int M, int N)
{
    __shared__ _Float16 Asl[64][136];
    __shared__ _Float16 Bsl[64][136];
    const int tid = threadIdx.x;
    const int n0 = blockIdx.x * 64;
    const int m0 = blockIdx.y * 64;

#pragma unroll
    for (int i = 0; i < 4; ++i) {
        int u = i * 256 + tid;
        int r = u >> 4;
        int c = u & 15;
        int row = m0 + r;
        int ar = (row < M) ? (gidx ? gidx[row] : row) : 0;
        *(float4*)&Asl[r][c * 8] = *(const float4*)(A + (size_t)ar * 128 + c * 8);
        *(float4*)&Bsl[r][c * 8] = *(const float4*)(B + (size_t)(n0 + r) * 128 + c * 8);
    }
    __syncthreads();

    const int wave = tid >> 6;
    const int lane = tid & 63;
    const int l15 = lane & 15;
    const int quad = lane >> 4;

    f32x4 acc[4];
#pragma unroll
    for (int mt = 0; mt < 4; ++mt) acc[mt] = (f32x4){0.f, 0.f, 0.f, 0.f};

#pragma unroll
    for (int ks = 0; ks < 4; ++ks) {
        half8 bfrag = *(const half8*)&Bsl[wave * 16 + l15][quad * 8 + ks * 32];
#pragma unroll
        for (int mt = 0; mt < 4; ++mt) {
            half8 afrag = *(const half8*)&Asl[mt * 16 + l15][quad * 8 + ks * 32];
            acc[mt] = __builtin_amdgcn_mfma_f32_16x16x32_f16(afrag, bfrag, acc[mt], 0, 0, 0);
        }
    }

    int col = n0 + wave * 16 + l15;
    float bv = bias[col];
#pragma unroll
    for (int mt = 0; mt < 4; ++mt) {
#pragma unroll
        for (int r = 0; r < 4; ++r) {
            int m = m0 + mt * 16 + quad * 4 + r;
            if (m < M) {
                float v = acc[mt][r] + bv;
                if constexpr (std::is_same<OutT, _Float16>::value)
                    C[(size_t)m * N + col] = (_Float16)v;
                else
                    C[(size_t)m * N + col] = v;
            }
        }
    }
}

// ---------------- CSR aggregate + leaky-relu + L2 normalize ----------------

__global__ __launch_bounds__(64) void aggregate_kernel(
    const _Float16* __restrict__ h, const int* __restrict__ offs,
    const unsigned* __restrict__ ew, float* __restrict__ enc_out,
    _Float16* __restrict__ enc_h)
{
    const int row = blockIdx.x;
    const int lane = threadIdx.x;
    const int beg = offs[row];
    const int end = offs[row + 1];
    float ax = 0.f, ay = 0.f;
#pragma unroll 4
    for (int e = beg; e < end; ++e) {
        unsigned p = ew[e];
        HBits cv; cv.u = (unsigned short)(p & 0xffffu);
        float w = (float)cv.h;
        int d = p >> 16;
        half2t hv = *(const half2t*)(h + (size_t)d * 128 + lane * 2);
        ax += w * (float)hv[0];
        ay += w * (float)hv[1];
    }
    ax = ax >= 0.f ? ax : 0.01f * ax;
    ay = ay >= 0.f ? ay : 0.01f * ay;
    float ss = ax * ax + ay * ay;
#pragma unroll
    for (int o = 32; o > 0; o >>= 1) ss += __shfl_xor(ss, o);
    float inv = 1.f / fmaxf(sqrtf(ss), 1e-12f);
    float ex = ax * inv, ey = ay * inv;
    *(float2*)(enc_out + (size_t)row * 128 + lane * 2) = make_float2(ex, ey);
    half2t hv = { (_Float16)ex, (_Float16)ey };
    *(half2t*)(enc_h + (size_t)row * 128 + lane * 2) = hv;
}

// ---------------- MFMA attention + mean + out_proj; block = session, wave = head ----------------
// S = Q K^T via mfma_f32_16x16x32_f16 (K-dim 32 = one step); exact softmax in regs
// (row = quad*4+r, cols across 16 lanes x 4 tiles); P -> LDS -> A-frag; PV via mfma;
// mean over L in-register (shfl ^16/^32); fused out_proj.

__global__ __launch_bounds__(256) void attn_mfma_kernel(
    const _Float16* __restrict__ qkv, const float* __restrict__ outw,
    const float* __restrict__ outb, float* __restrict__ out)
{
    const int b = blockIdx.x;
    const int wave = threadIdx.x >> 6;   // head
    const int lane = threadIdx.x & 63;
    const int l15 = lane & 15;
    const int quad = lane >> 4;
    __shared__ _Float16 pP[NHEADS][64][72];   // P matrix (softmax probs)
    __shared__ _Float16 vT[NHEADS][32][72];   // V transposed [j][m]
    __shared__ float ob[128];
    const _Float16* base = qkv + (size_t)b * SEQL * 384;

    // stage V^T: lane m scatters its V row
    {
        const _Float16* vrow = base + (size_t)lane * 384 + 256 + wave * 32;
        half8 v0 = *(const half8*)(vrow);
        half8 v1 = *(const half8*)(vrow + 8);
        half8 v2 = *(const half8*)(vrow + 16);
        half8 v3 = *(const half8*)(vrow + 24);
#pragma unroll
        for (int j = 0; j < 8; ++j) {
            vT[wave][j][lane]      = v0[j];
            vT[wave][j + 8][lane]  = v1[j];
            vT[wave][j + 16][lane] = v2[j];
            vT[wave][j + 24][lane] = v3[j];
        }
    }

    // Q / K fragments straight from global (A-layout: row=l15, k=quad*8+j)
    half8 qf[4], kf[4];
#pragma unroll
    for (int t = 0; t < 4; ++t) {
        qf[t] = *(const half8*)(base + (size_t)(t * 16 + l15) * 384 + wave * 32 + quad * 8);
        kf[t] = *(const half8*)(base + (size_t)(t * 16 + l15) * 384 + 128 + wave * 32 + quad * 8);
    }

    f32x4 S[4][4];
#pragma unroll
    for (int lt = 0; lt < 4; ++lt)
#pragma unroll
        for (int mt = 0; mt < 4; ++mt) S[lt][mt] = (f32x4){0.f, 0.f, 0.f, 0.f};
#pragma unroll
    for (int lt = 0; lt < 4; ++lt)
#pragma unroll
        for (int mt = 0; mt < 4; ++mt)
            S[lt][mt] = __builtin_amdgcn_mfma_f32_16x16x32_f16(qf[lt], kf[mt], S[lt][mt], 0, 0, 0);

    const float scale = 0.17677669529663687f;  // 1/sqrt(32)
#pragma unroll
    for (int lt = 0; lt < 4; ++lt) {
#pragma unroll
        for (int r = 0; r < 4; ++r) {
            float m0 = -1e30f;
#pragma unroll
            for (int mt = 0; mt < 4; ++mt) {
                S[lt][mt][r] *= scale;
                m0 = fmaxf(m0, S[lt][mt][r]);
            }
#pragma unroll
            for (int o = 1; o < 16; o <<= 1) m0 = fmaxf(m0, __shfl_xor(m0, o));
            float s0 = 0.f;
#pragma unroll
            for (int mt = 0; mt < 4; ++mt) {
                float p = __expf(S[lt][mt][r] - m0);
                S[lt][mt][r] = p;
                s0 += p;
            }
#pragma unroll
            for (int o = 1; o < 16; o <<= 1) s0 += __shfl_xor(s0, o);
            float inv = 1.f / s0;
#pragma unroll
            for (int mt = 0; mt < 4; ++mt)
                pP[wave][lt * 16 + quad * 4 + r][mt * 16 + l15] = (_Float16)(S[lt][mt][r] * inv);
        }
    }
    __syncthreads();

    // O = P V : contraction over m (64) in 2 steps
    f32x4 O[4][2];
#pragma unroll
    for (int lt = 0; lt < 4; ++lt)
#pragma unroll
        for (int jt = 0; jt < 2; ++jt) O[lt][jt] = (f32x4){0.f, 0.f, 0.f, 0.f};
#pragma unroll
    for (int kh = 0; kh < 2; ++kh) {
        half8 vf[2];
#pragma unroll
        for (int jt = 0; jt < 2; ++jt)
            vf[jt] = *(const half8*)&vT[wave][jt * 16 + l15][kh * 32 + quad * 8];
#pragma unroll
        for (int lt = 0; lt < 4; ++lt) {
            half8 pf = *(const half8*)&pP[wave][lt * 16 + l15][kh * 32 + quad * 8];
#pragma unroll
            for (int jt = 0; jt < 2; ++jt)
                O[lt][jt] = __builtin_amdgcn_mfma_f32_16x16x32_f16(pf, vf[jt], O[lt][jt], 0, 0, 0);
        }
    }

    // mean over the 64 query rows -> ob[head*32 + j]
#pragma unroll
    for (int jt = 0; jt < 2; ++jt) {
        float part = 0.f;
#pragma unroll
        for (int lt = 0; lt < 4; ++lt)
#pragma unroll
            for (int r = 0; r < 4; ++r) part += O[lt][jt][r];
        part += __shfl_xor(part, 16);
        part += __shfl_xor(part, 32);
        if (quad == 0) ob[wave * 32 + jt * 16 + l15] = part * (1.f / 64.f);
    }
    __syncthreads();

    int t = threadIdx.x;
    if (t < 128) {
        float val = outb[t];
        const float* wrow = outw + (size_t)t * 128;
#pragma unroll 8
        for (int k4 = 0; k4 < 32; ++k4) {
            float4 wv = *(const float4*)(wrow + k4 * 4);
            val += wv.x * ob[k4 * 4] + wv.y * ob[k4 * 4 + 1]
                 + wv.z * ob[k4 * 4 + 2] + wv.w * ob[k4 * 4 + 3];
        }
        out[(size_t)b * 128 + t] = val;
    }
}

// ---------------- tar_embed gather ----------------

__global__ void tar_kernel(const float* __restrict__ enc, const int* __restrict__ data_poi,
                           float* __restrict__ out)
{
    int i = blockIdx.x * blockDim.x + threadIdx.x;
    if (i >= BATCH * 128) return;
    int r = i >> 7, c = i & 127;
    out[i] = enc[(size_t)data_poi[r] * 128 + c];
}

// ---------------- launch ----------------

extern "C" void kernel_launch(void* const* d_in, const int* in_sizes, int n_in,
                              void* d_out, int out_size, void* d_ws, size_t ws_size,
                              hipStream_t stream)
{
    const float* poi      = (const float*)d_in[0];
    const int*   edges    = (const int*)d_in[1];
    const float* dvec     = (const float*)d_in[2];
    const int*   data_poi = (const int*)d_in[3];
    const int*   data_x   = (const int*)d_in[4];
    const float* lin_w    = (const float*)d_in[5];
    const float* lin_b    = (const float*)d_in[6];
    const float* inw      = (const float*)d_in[7];
    const float* inb      = (const float*)d_in[8];
    const float* outw     = (const float*)d_in[9];
    const float* outb     = (const float*)d_in[10];
    const int* e0 = edges;
    const int* e1 = edges + NEDGE;

    char* ws = (char*)d_ws;
    size_t off = 0;
    auto alloc = [&](size_t bytes) -> void* {
        void* p = ws + off;
        off = (off + bytes + 255) & ~(size_t)255;
        return p;
    };
    int*      counts = (int*)     alloc(NPOI * 4);
    int*      offs   = (int*)     alloc((NPOI + 1) * 4);
    int*      bsum   = (int*)     alloc(SCAN_BLOCKS * 4);
    int*      bcur   = (int*)     alloc(NB * 4);
    float*    rd     = (float*)   alloc(NPOI * 4);
    unsigned* ew     = (unsigned*)alloc((size_t)EAUG * 4);
    float*    enc    = (float*)   alloc((size_t)NPOI * 128 * 4);
    _Float16* enc_h  = (_Float16*)alloc((size_t)NPOI * 128 * 2);
    _Float16* linw_h = (_Float16*)alloc((size_t)2 * 128 * 128 * 2);
    _Float16* inw_h  = (_Float16*)alloc((size_t)384 * 128 * 2);
    char*     big    = (char*)    alloc(50ull * 1024 * 1024);
    // aliases inside the big region (lifetimes strictly ordered):
    //   poi_h   [ 0, 12.8 MB)  — cvt -> GEMM1
    //   staging [16, 32.1 MB)  — partition -> hist/csr_sort
    //   hbuf    [33, 45.8 MB)  — GEMM1/2 -> aggregate
    //   qkv_h   [ 0, 25.2 MB)  — qkv GEMM (after all above dead) -> attn
    _Float16* poi_h   = (_Float16*)big;
    u64*      staging = (u64*)(big + 16ull * 1024 * 1024);
    _Float16* hbuf    = (_Float16*)(big + 33ull * 1024 * 1024);
    _Float16* qkv_h   = (_Float16*)big;

    cvt_all_kernel<<<(N4_POI + N4_LIN + N4_INW + 255) / 256, 256, 0, stream>>>(
        poi, lin_w, inw, poi_h, linw_h, inw_h);

    init_bcur_kernel<<<1, 256, 0, stream>>>(bcur);
    partition_kernel<<<P1_BLOCKS, 256, 0, stream>>>(e0, e1, dvec, bcur, staging);
    hist_kernel<<<NB, 256, 0, stream>>>(staging, bcur, counts, bsum);
    scan_chunk_kernel<<<SCAN_BLOCKS, 256, 0, stream>>>(counts, bsum, offs, rd);
    csr_sort_kernel<<<NB, 256, 0, stream>>>(staging, bcur, offs, rd, ew);

    // 2 graph-conv layers
    gemm_mfma_f16<_Float16><<<dim3(2, (NPOI + 63) / 64), 256, 0, stream>>>(
        poi_h, nullptr, linw_h, lin_b, hbuf, NPOI, 128);
    aggregate_kernel<<<NPOI, 64, 0, stream>>>(hbuf, offs, ew, enc, enc_h);
    gemm_mfma_f16<_Float16><<<dim3(2, (NPOI + 63) / 64), 256, 0, stream>>>(
        enc_h, nullptr, linw_h + 128 * 128, lin_b + 128, hbuf, NPOI, 128);
    aggregate_kernel<<<NPOI, 64, 0, stream>>>(hbuf, offs, ew, enc, enc_h);

    // attention (qkv gemm fp16 -> MFMA attn + mean + out_proj -> d_out)
    gemm_mfma_f16<_Float16><<<dim3(6, BATCH * SEQL / 64), 256, 0, stream>>>(
        enc_h, data_x, inw_h, inb, qkv_h, BATCH * SEQL, 384);
    attn_mfma_kernel<<<BATCH, 256, 0, stream>>>(qkv_h, outw, outb, (float*)d_out);

    tar_kernel<<<(BATCH * 128 + 255) / 256, 256, 0, stream>>>(
        enc, data_poi, (float*)d_out + BATCH * 128);
}

// Round 10
// 288.466 us; speedup vs baseline: 3.3059x; 1.0649x over previous
//
#include <hip/hip_runtime.h>
#include <hip/hip_fp16.h>

#define NPOI 50000
#define EMB 128
#define NEDGE 800000
#define EAUG (2 * NEDGE + NPOI)
#define BATCH 512
#define SEQL 64
#define NHEADS 4
#define HDIM 32
#define NB 196                              // 256-node buckets
#define P1_BLOCKS ((NEDGE + 2047) / 2048)   // 391
#define SLAB_CAP 10240
#define BUCKET_CAP 10240

typedef _Float16 half8 __attribute__((ext_vector_type(8)));
typedef _Float16 half4 __attribute__((ext_vector_type(4)));
typedef _Float16 half2t __attribute__((ext_vector_type(2)));
typedef float f32x4 __attribute__((ext_vector_type(4)));
typedef unsigned long long u64;

union HBits { _Float16 h; unsigned short u; };

// ---------------- fused fp32 -> fp16 convert (poi, lin_w, in_proj_w) + bcur init ----------------

#define N4_POI (NPOI * 128 / 4)
#define N4_LIN (2 * 128 * 128 / 4)
#define N4_INW (384 * 128 / 4)
#define CVT_TOT (N4_POI + N4_LIN + N4_INW + NB)

__global__ void cvt_all_kernel(const float* __restrict__ poi, const float* __restrict__ linw,
                               const float* __restrict__ inw,
                               _Float16* __restrict__ poi_h, _Float16* __restrict__ linw_h,
                               _Float16* __restrict__ inw_h, int* __restrict__ bcur) {
    int i = blockIdx.x * blockDim.x + threadIdx.x;
    const float* src; _Float16* dst; int j = i;
    if (i < N4_POI) { src = poi; dst = poi_h; }
    else if (i < N4_POI + N4_LIN) { j = i - N4_POI; src = linw; dst = linw_h; }
    else if (i < N4_POI + N4_LIN + N4_INW) { j = i - N4_POI - N4_LIN; src = inw; dst = inw_h; }
    else if (i < CVT_TOT) { int b = i - (N4_POI + N4_LIN + N4_INW); bcur[b] = b * SLAB_CAP; return; }
    else return;
    float4 v = ((const float4*)src)[j];
    half4 h = { (_Float16)v.x, (_Float16)v.y, (_Float16)v.z, (_Float16)v.w };
    ((half4*)dst)[j] = h;
}

// ---------------- phase 1: LDS-buffered multisplit into static per-bucket slabs ----------------

__global__ __launch_bounds__(256) void partition_kernel(
    const int* __restrict__ e0, const int* __restrict__ e1,
    const float* __restrict__ dv, int* __restrict__ bcur,
    u64* __restrict__ staging)
{
    __shared__ u64 stg[4096];
    __shared__ int lh[NB], lbase[NB], gb[NB];
    __shared__ int sc[256];
    const int t = threadIdx.x;
    const int blockBase = blockIdx.x * 2048;
    for (int j = t; j < NB; j += 256) lh[j] = 0;
    __syncthreads();

    u64 vals[16];
    unsigned br[16];
#pragma unroll
    for (int i = 0; i < 8; ++i) {
        br[2 * i] = 0xFFFFFFFFu;
        br[2 * i + 1] = 0xFFFFFFFFu;
        int g = blockBase + i * 256 + t;
        if (g < NEDGE) {
            int s = e0[g], d = e1[g];
            unsigned db = __float_as_uint(dv[g]);
            vals[2 * i]     = ((u64)s << 48) | ((u64)d << 32) | db;
            vals[2 * i + 1] = ((u64)d << 48) | ((u64)s << 32) | db;
            int bs = s >> 8, bd = d >> 8;
            int rs = atomicAdd(&lh[bs], 1);
            int rd_ = atomicAdd(&lh[bd], 1);
            br[2 * i]     = ((unsigned)bs << 16) | (unsigned)rs;
            br[2 * i + 1] = ((unsigned)bd << 16) | (unsigned)rd_;
        }
    }
    __syncthreads();
    sc[t] = (t < NB) ? lh[t] : 0;
    __syncthreads();
    for (int o = 1; o < 256; o <<= 1) {
        int u = (t >= o) ? sc[t - o] : 0;
        __syncthreads();
        sc[t] += u;
        __syncthreads();
    }
    if (t < NB) {
        lbase[t] = sc[t] - lh[t];
        gb[t] = (lh[t] > 0) ? atomicAdd(&bcur[t], lh[t]) : 0;
    }
    __syncthreads();
#pragma unroll
    for (int i = 0; i < 16; ++i) {
        if (br[i] != 0xFFFFFFFFu) {
            int b = br[i] >> 16, r = br[i] & 0xFFFF;
            stg[lbase[b] + r] = vals[i];
        }
    }
    __syncthreads();
    const int total = sc[255];
    for (int j = t; j < total; j += 256) {
        u64 v = stg[j];
        int b = (int)(v >> 56);
        staging[(size_t)gb[b] + (unsigned)(j - lbase[b])] = v;
    }
}

// ---------------- per-bucket histogram -> rd = rsqrt(deg), bsum ----------------

__global__ __launch_bounds__(256) void hist_kernel(const u64* __restrict__ staging,
                                                   const int* __restrict__ bcur,
                                                   float* __restrict__ rd,
                                                   int* __restrict__ bsum) {
    __shared__ int cnt[256];
    __shared__ int red[256];
    const int b = blockIdx.x, t = threadIdx.x;
    cnt[t] = 0;
    __syncthreads();
    const int base = b * SLAB_CAP;
    const int n = bcur[b] - base;
    for (int j = t; j < n; j += 256)
        atomicAdd(&cnt[(int)(staging[base + j] >> 48) & 255], 1);
    __syncthreads();
    int node = b * 256 + t;
    int rowsz = 0;
    if (node < NPOI) {
        rowsz = cnt[t] + 1;   // + self loop
        rd[node] = rsqrtf((float)rowsz);
    }
    red[t] = rowsz;
    __syncthreads();
    for (int o = 128; o > 0; o >>= 1) {
        if (t < o) red[t] += red[t + o];
        __syncthreads();
    }
    if (t == 0) bsum[b] = red[0];
}

// ---------------- phase 2: per-bucket counting sort + weights + offs -> packed CSR ----------------

__global__ __launch_bounds__(256) void csr_sort_kernel(
    const u64* __restrict__ staging, const int* __restrict__ bcur,
    const int* __restrict__ bsum, const float* __restrict__ rd,
    int* __restrict__ offs, unsigned* __restrict__ ew)
{
    const int k = blockIdx.x;
    const int node0 = k * 256;
    __shared__ unsigned outb[BUCKET_CAP];
    __shared__ int cnt[256], base2[256];
    __shared__ float rdl[256];
    __shared__ int bb_sh;
    const int t = threadIdx.x;
    const int node = node0 + t;
    cnt[t] = 0;
    rdl[t] = (node < NPOI) ? rd[node] : 0.f;
    // bucket base = prefix sum of bsum[0..k-1]
    {
        int partial = 0;
        for (int j = t; j < k; j += 256) partial += bsum[j];
        base2[t] = partial;
        __syncthreads();
        for (int o = 128; o > 0; o >>= 1) {
            if (t < o) base2[t] += base2[t + o];
            __syncthreads();
        }
        if (t == 0) bb_sh = base2[0];
        __syncthreads();
    }
    const int bucketbase = bb_sh;
    __syncthreads();
    const int sb = k * SLAB_CAP;
    const int n = bcur[k] - sb;
    for (int j = t; j < n; j += 256)
        atomicAdd(&cnt[(int)(staging[sb + j] >> 48) & 255], 1);
    __syncthreads();
    int rowsz = (node < NPOI) ? cnt[t] + 1 : 0;
    base2[t] = rowsz;
    __syncthreads();
    for (int o = 1; o < 256; o <<= 1) {
        int u = (t >= o) ? base2[t - o] : 0;
        __syncthreads();
        base2[t] += u;
        __syncthreads();
    }
    int myexc = base2[t] - rowsz;
    __syncthreads();
    base2[t] = myexc;
    cnt[t] = 0;
    if (node < NPOI) {
        offs[node] = bucketbase + myexc;
        if (node == NPOI - 1) offs[NPOI] = bucketbase + myexc + rowsz;
    }
    __syncthreads();
    for (int j = t; j < n; j += 256) {
        u64 e = staging[sb + j];
        int sl = (int)(e >> 48) & 255;
        int d = (int)(e >> 32) & 0xFFFF;
        float dist = __uint_as_float((unsigned)e);
        float w = rdl[sl] * rd[d] * expf(-dist * dist);
        HBits cv; cv.h = (_Float16)w;
        int r = atomicAdd(&cnt[sl], 1);
        outb[base2[sl] + r] = ((unsigned)d << 16) | cv.u;
    }
    __syncthreads();
    if (node < NPOI) {   // self loop in last slot of the row
        float w = rdl[t] * rdl[t];
        HBits cv; cv.h = (_Float16)w;
        outb[base2[t] + cnt[t]] = ((unsigned)node << 16) | cv.u;
    }
    __syncthreads();
    const int ntot = (node0 + 256 < NPOI ? n + 256 : n + (NPOI - node0));
    for (int j = t; j < ntot; j += 256) ew[bucketbase + j] = outb[j];   // coalesced
}

// ---------------- fp16 MFMA GEMM: C[M,N] = A(gathered)[M,128] @ B[N,128]^T + bias ----------------
// epilogue: C tile transposed through LDS -> 16B/lane coalesced fp16 stores (64 cols = 8 chunks!)

__global__ __launch_bounds__(256) void gemm_mfma_f16(
    const _Float16* __restrict__ A, const int* __restrict__ gidx,
    const _Float16* __restrict__ B, const float* __restrict__ bias,
    _Float16* __restrict__ C, int M, int N)
{
    __shared__ _Float16 Asl[64][136];
    __shared__ _Float16 Bsl[64][136];
    const int tid = threadIdx.x;
    const int n0 = blockIdx.x * 64;
    const int m0 = blockIdx.y * 64;

#pragma unroll
    for (int i = 0; i < 4; ++i) {
        int u = i * 256 + tid;
        int r = u >> 4;
        int c = u & 15;
        int row = m0 + r;
        int ar = (row < M) ? (gidx ? gidx[row] : row) : 0;
        *(float4*)&Asl[r][c * 8] = *(const float4*)(A + (size_t)ar * 128 + c * 8);
        *(float4*)&Bsl[r][c * 8] = *(const float4*)(B + (size_t)(n0 + r) * 128 + c * 8);
    }
    __syncthreads();

    const int wave = tid >> 6;
    const int lane = tid & 63;
    const int l15 = lane & 15;
    const int quad = lane >> 4;

    f32x4 acc[4];
#pragma unroll
    for (int mt = 0; mt < 4; ++mt) acc[mt] = (f32x4){0.f, 0.f, 0.f, 0.f};

#pragma unroll
    for (int ks = 0; ks < 4; ++ks) {
        half8 bfrag = *(const half8*)&Bsl[wave * 16 + l15][quad * 8 + ks * 32];
#pragma unroll
        for (int mt = 0; mt < 4; ++mt) {
            half8 afrag = *(const half8*)&Asl[mt * 16 + l15][quad * 8 + ks * 32];
            acc[mt] = __builtin_amdgcn_mfma_f32_16x16x32_f16(afrag, bfrag, acc[mt], 0, 0, 0);
        }
    }

    // transpose C tile through LDS (reuse Asl) for vectorized stores
    const int col = wave * 16 + l15;
    const float bv = bias[n0 + col];
    __syncthreads();
#pragma unroll
    for (int mt = 0; mt < 4; ++mt)
#pragma unroll
        for (int r = 0; r < 4; ++r)
            Asl[mt * 16 + quad * 4 + r][col] = (_Float16)(acc[mt][r] + bv);
    __syncthreads();
    // 64 rows x 8 chunks (64 cols) = 512 units; 16B/lane coalesced
#pragma unroll
    for (int i = 0; i < 2; ++i) {
        int u = i * 256 + tid;
        int r = u >> 3;          // 0..63 row in tile
        int c = u & 7;           // 0..7  8-half chunk within the 64-col tile
        int m = m0 + r;
        if (m < M)
            *(half8*)(C + (size_t)m * N + n0 + c * 8) = *(const half8*)&Asl[r][c * 8];
    }
}

// ---------------- CSR aggregate + leaky-relu + L2 normalize ----------------

__global__ __launch_bounds__(64) void aggregate_kernel(
    const _Float16* __restrict__ h, const int* __restrict__ offs,
    const unsigned* __restrict__ ew, float* __restrict__ enc_out,
    _Float16* __restrict__ enc_h)
{
    const int row = blockIdx.x;
    const int lane = threadIdx.x;
    const int beg = offs[row];
    const int end = offs[row + 1];
    float ax = 0.f, ay = 0.f;
#pragma unroll 8
    for (int e = beg; e < end; ++e) {
        unsigned p = ew[e];
        HBits cv; cv.u = (unsigned short)(p & 0xffffu);
        float w = (float)cv.h;
        int d = p >> 16;
        half2t hv = *(const half2t*)(h + (size_t)d * 128 + lane * 2);
        ax += w * (float)hv[0];
        ay += w * (float)hv[1];
    }
    ax = ax >= 0.f ? ax : 0.01f * ax;
    ay = ay >= 0.f ? ay : 0.01f * ay;
    float ss = ax * ax + ay * ay;
#pragma unroll
    for (int o = 32; o > 0; o >>= 1) ss += __shfl_xor(ss, o);
    float inv = 1.f / fmaxf(sqrtf(ss), 1e-12f);
    float ex = ax * inv, ey = ay * inv;
    *(float2*)(enc_out + (size_t)row * 128 + lane * 2) = make_float2(ex, ey);
    half2t hv = { (_Float16)ex, (_Float16)ey };
    *(half2t*)(enc_h + (size_t)row * 128 + lane * 2) = hv;
}

// ---------------- MFMA attention + mean + out_proj + fused tar gather ----------------

__global__ __launch_bounds__(256) void attn_mfma_kernel(
    const _Float16* __restrict__ qkv, const float* __restrict__ outw,
    const float* __restrict__ outb, const float* __restrict__ enc,
    const int* __restrict__ data_poi, float* __restrict__ out)
{
    const int b = blockIdx.x;
    const int wave = threadIdx.x >> 6;   // head
    const int lane = threadIdx.x & 63;
    const int l15 = lane & 15;
    const int quad = lane >> 4;
    __shared__ _Float16 pP[NHEADS][64][72];
    __shared__ _Float16 vT[NHEADS][32][72];
    __shared__ float ob[128];
    const _Float16* base = qkv + (size_t)b * SEQL * 384;

    // stage V^T: lane m scatters its V row
    {
        const _Float16* vrow = base + (size_t)lane * 384 + 256 + wave * 32;
        half8 v0 = *(const half8*)(vrow);
        half8 v1 = *(const half8*)(vrow + 8);
        half8 v2 = *(const half8*)(vrow + 16);
        half8 v3 = *(const half8*)(vrow + 24);
#pragma unroll
        for (int j = 0; j < 8; ++j) {
            vT[wave][j][lane]      = v0[j];
            vT[wave][j + 8][lane]  = v1[j];
            vT[wave][j + 16][lane] = v2[j];
            vT[wave][j + 24][lane] = v3[j];
        }
    }

    // Q / K fragments straight from global (A-layout: row=l15, k=quad*8+j)
    half8 qf[4], kf[4];
#pragma unroll
    for (int t = 0; t < 4; ++t) {
        qf[t] = *(const half8*)(base + (size_t)(t * 16 + l15) * 384 + wave * 32 + quad * 8);
        kf[t] = *(const half8*)(base + (size_t)(t * 16 + l15) * 384 + 128 + wave * 32 + quad * 8);
    }

    f32x4 S[4][4];
#pragma unroll
    for (int lt = 0; lt < 4; ++lt)
#pragma unroll
        for (int mt = 0; mt < 4; ++mt) S[lt][mt] = (f32x4){0.f, 0.f, 0.f, 0.f};
#pragma unroll
    for (int lt = 0; lt < 4; ++lt)
#pragma unroll
        for (int mt = 0; mt < 4; ++mt)
            S[lt][mt] = __builtin_amdgcn_mfma_f32_16x16x32_f16(qf[lt], kf[mt], S[lt][mt], 0, 0, 0);

    const float scale = 0.17677669529663687f;  // 1/sqrt(32)
#pragma unroll
    for (int lt = 0; lt < 4; ++lt) {
#pragma unroll
        for (int r = 0; r < 4; ++r) {
            float m0 = -1e30f;
#pragma unroll
            for (int mt = 0; mt < 4; ++mt) {
                S[lt][mt][r] *= scale;
                m0 = fmaxf(m0, S[lt][mt][r]);
            }
#pragma unroll
            for (int o = 1; o < 16; o <<= 1) m0 = fmaxf(m0, __shfl_xor(m0, o));
            float s0 = 0.f;
#pragma unroll
            for (int mt = 0; mt < 4; ++mt) {
                float p = __expf(S[lt][mt][r] - m0);
                S[lt][mt][r] = p;
                s0 += p;
            }
#pragma unroll
            for (int o = 1; o < 16; o <<= 1) s0 += __shfl_xor(s0, o);
            float inv = 1.f / s0;
#pragma unroll
            for (int mt = 0; mt < 4; ++mt)
                pP[wave][lt * 16 + quad * 4 + r][mt * 16 + l15] = (_Float16)(S[lt][mt][r] * inv);
        }
    }
    __syncthreads();

    // O = P V : contraction over m (64) in 2 steps
    f32x4 O[4][2];
#pragma unroll
    for (int lt = 0; lt < 4; ++lt)
#pragma unroll
        for (int jt = 0; jt < 2; ++jt) O[lt][jt] = (f32x4){0.f, 0.f, 0.f, 0.f};
#pragma unroll
    for (int kh = 0; kh < 2; ++kh) {
        half8 vf[2];
#pragma unroll
        for (int jt = 0; jt < 2; ++jt)
            vf[jt] = *(const half8*)&vT[wave][jt * 16 + l15][kh * 32 + quad * 8];
#pragma unroll
        for (int lt = 0; lt < 4; ++lt) {
            half8 pf = *(const half8*)&pP[wave][lt * 16 + l15][kh * 32 + quad * 8];
#pragma unroll
            for (int jt = 0; jt < 2; ++jt)
                O[lt][jt] = __builtin_amdgcn_mfma_f32_16x16x32_f16(pf, vf[jt], O[lt][jt], 0, 0, 0);
        }
    }

    // mean over the 64 query rows -> ob[head*32 + j]
#pragma unroll
    for (int jt = 0; jt < 2; ++jt) {
        float part = 0.f;
#pragma unroll
        for (int lt = 0; lt < 4; ++lt)
#pragma unroll
            for (int r = 0; r < 4; ++r) part += O[lt][jt][r];
        part += __shfl_xor(part, 16);
        part += __shfl_xor(part, 32);
        if (quad == 0) ob[wave * 32 + jt * 16 + l15] = part * (1.f / 64.f);
    }
    __syncthreads();

    int t = threadIdx.x;
    if (t < 128) {
        float val = outb[t];
        const float* wrow = outw + (size_t)t * 128;
#pragma unroll 8
        for (int k4 = 0; k4 < 32; ++k4) {
            float4 wv = *(const float4*)(wrow + k4 * 4);
            val += wv.x * ob[k4 * 4] + wv.y * ob[k4 * 4 + 1]
                 + wv.z * ob[k4 * 4 + 2] + wv.w * ob[k4 * 4 + 3];
        }
        out[(size_t)b * 128 + t] = val;
    } else {
        // fused tar_embed gather: threads 128..255 handle out2[b][j]
        int j = t - 128;
        out[(size_t)(BATCH + b) * 128 + j] = enc[(size_t)data_poi[b] * 128 + j];
    }
}

// ---------------- launch ----------------

extern "C" void kernel_launch(void* const* d_in, const int* in_sizes, int n_in,
                              void* d_out, int out_size, void* d_ws, size_t ws_size,
                              hipStream_t stream)
{
    const float* poi      = (const float*)d_in[0];
    const int*   edges    = (const int*)d_in[1];
    const float* dvec     = (const float*)d_in[2];
    const int*   data_poi = (const int*)d_in[3];
    const int*   data_x   = (const int*)d_in[4];
    const float* lin_w    = (const float*)d_in[5];
    const float* lin_b    = (const float*)d_in[6];
    const float* inw      = (const float*)d_in[7];
    const float* inb      = (const float*)d_in[8];
    const float* outw     = (const float*)d_in[9];
    const float* outb     = (const float*)d_in[10];
    const int* e0 = edges;
    const int* e1 = edges + NEDGE;

    char* ws = (char*)d_ws;
    size_t off = 0;
    auto alloc = [&](size_t bytes) -> void* {
        void* p = ws + off;
        off = (off + bytes + 255) & ~(size_t)255;
        return p;
    };
    int*      offs   = (int*)     alloc((NPOI + 1) * 4);
    int*      bsum   = (int*)     alloc(NB * 4);
    int*      bcur   = (int*)     alloc(NB * 4);
    float*    rd     = (float*)   alloc(NPOI * 4);
    unsigned* ew     = (unsigned*)alloc((size_t)EAUG * 4);
    float*    enc    = (float*)   alloc((size_t)NPOI * 128 * 4);
    _Float16* enc_h  = (_Float16*)alloc((size_t)NPOI * 128 * 2);
    _Float16* linw_h = (_Float16*)alloc((size_t)2 * 128 * 128 * 2);
    _Float16* inw_h  = (_Float16*)alloc((size_t)384 * 128 * 2);
    char*     big    = (char*)    alloc(50ull * 1024 * 1024);
    // aliases inside the big region (lifetimes strictly ordered):
    //   poi_h   [ 0, 12.8 MB)  — cvt -> GEMM1
    //   staging [16, 32.1 MB)  — partition -> hist/csr_sort
    //   hbuf    [33, 45.8 MB)  — GEMM1/2 -> aggregate
    //   qkv_h   [ 0, 25.2 MB)  — qkv GEMM (after all above dead) -> attn
    _Float16* poi_h   = (_Float16*)big;
    u64*      staging = (u64*)(big + 16ull * 1024 * 1024);
    _Float16* hbuf    = (_Float16*)(big + 33ull * 1024 * 1024);
    _Float16* qkv_h   = (_Float16*)big;

    cvt_all_kernel<<<(CVT_TOT + 255) / 256, 256, 0, stream>>>(
        poi, lin_w, inw, poi_h, linw_h, inw_h, bcur);

    partition_kernel<<<P1_BLOCKS, 256, 0, stream>>>(e0, e1, dvec, bcur, staging);
    hist_kernel<<<NB, 256, 0, stream>>>(staging, bcur, rd, bsum);
    csr_sort_kernel<<<NB, 256, 0, stream>>>(staging, bcur, bsum, rd, offs, ew);

    // 2 graph-conv layers
    gemm_mfma_f16<<<dim3(2, (NPOI + 63) / 64), 256, 0, stream>>>(
        poi_h, nullptr, linw_h, lin_b, hbuf, NPOI, 128);
    aggregate_kernel<<<NPOI, 64, 0, stream>>>(hbuf, offs, ew, enc, enc_h);
    gemm_mfma_f16<<<dim3(2, (NPOI + 63) / 64), 256, 0, stream>>>(
        enc_h, nullptr, linw_h + 128 * 128, lin_b + 128, hbuf, NPOI, 128);
    aggregate_kernel<<<NPOI, 64, 0, stream>>>(hbuf, offs, ew, enc, enc_h);

    // attention (qkv gemm fp16 -> MFMA attn + mean + out_proj + tar -> d_out)
    gemm_mfma_f16<<<dim3(6, BATCH * SEQL / 64), 256, 0, stream>>>(
        enc_h, data_x, inw_h, inb, qkv_h, BATCH * SEQL, 384);
    attn_mfma_kernel<<<BATCH, 256, 0, stream>>>(qkv_h, outw, outb, enc, data_poi, (float*)d_out);
}